// Round 1
// baseline (694.569 us; speedup 1.0000x reference)
//
#include <hip/hip_runtime.h>
#include <math.h>

#define EPS 1e-5f
#define BT 1536
#define NP 128     // positions = 16*8
#define FD 8192    // 64*128

// ---------------- prep: pack conv2 weights (o,c,9) -> (o,c,12) ----------------
__global__ void k_pack_w2(const float* __restrict__ w2, float* __restrict__ w2p) {
    int i = blockIdx.x * 256 + threadIdx.x;   // over 64*64*12
    if (i >= 64 * 64 * 12) return;
    int k = i % 12, oc = i / 12;
    w2p[i] = (k < 9) ? w2[oc * 9 + k] : 0.f;
}

// ---------------- prep: lc weight transpose (o,c,p) -> (p,c,o) ----------------
// one block per input-channel-slice c; blockIdx.y selects lc1 vs lc2
__global__ __launch_bounds__(256) void k_t_lc(const float* __restrict__ w_lc1,
                                              const float* __restrict__ w_lc2,
                                              float* __restrict__ o1, float* __restrict__ o2) {
    const int c = blockIdx.x;
    const float* in = blockIdx.y ? w_lc2 : w_lc1;
    float* out = blockIdx.y ? o2 : o1;
    __shared__ float tl[64][132];
    const int t = threadIdx.x;
    {   // load rows: in[(o*64+c)*128 + p]
        int o = t & 63, seg = t >> 6;  // 4 segs x 32 p
        const float* r = in + (size_t)(o * 64 + c) * 128 + seg * 32;
#pragma unroll
        for (int q = 0; q < 8; ++q) {
            float4 v = ((const float4*)r)[q];
            *(float4*)&tl[o][seg * 32 + q * 4] = v;
        }
    }
    __syncthreads();
    {   // write: out[(p*64 + c)*64 + o]
        int ol = t & 15, pr = t >> 4;
#pragma unroll
        for (int pass = 0; pass < 8; ++pass) {
            int p = pass * 16 + pr;
            float4 v = make_float4(tl[ol * 4 + 0][p], tl[ol * 4 + 1][p],
                                   tl[ol * 4 + 2][p], tl[ol * 4 + 3][p]);
            *(float4*)(out + (size_t)(p * 64 + c) * 64 + ol * 4) = v;
        }
    }
}

// -------- prep: generic weight transpose (R,C)->(C,R), optional fc1 k-perm -----
// out[perm(c)*R + r] = in[r*C + c];  perm(k) = (k&127)*64 + (k>>7) for fc1
template <bool FC1PERM>
__global__ __launch_bounds__(256) void k_t_w(const float* __restrict__ in,
                                             float* __restrict__ out, int R, int C) {
    __shared__ float tl[64][68];
    const int t = threadIdx.x;
    const int c0 = blockIdx.x * 64, r0 = blockIdx.y * 64;
    {
        int kl = t & 15, rr = t >> 4;
#pragma unroll
        for (int pass = 0; pass < 4; ++pass) {
            int r = rr + pass * 16;
            float4 v = *(const float4*)(in + (size_t)(r0 + r) * C + c0 + kl * 4);
            *(float4*)&tl[r][kl * 4] = v;
        }
    }
    __syncthreads();
    {
        int jl = t & 15, kk = t >> 4;
#pragma unroll
        for (int pass = 0; pass < 4; ++pass) {
            int cc = kk + pass * 16;
            int c = c0 + cc;
            int orow = FC1PERM ? ((c & 127) * 64 + (c >> 7)) : c;
            float4 v = make_float4(tl[jl * 4 + 0][cc], tl[jl * 4 + 1][cc],
                                   tl[jl * 4 + 2][cc], tl[jl * 4 + 3][cc]);
            *(float4*)(out + (size_t)orow * R + r0 + jl * 4) = v;
        }
    }
}

// ---------------- K1: bn0 + conv1 + bn1relu + conv2 + bn2relu ----------------
// one block per sample; act out layout (b, p, c)
__global__ __launch_bounds__(256) void k_conv(
    const float* __restrict__ inA, const float* __restrict__ inP, const float* __restrict__ inN,
    const float* __restrict__ bn0g, const float* __restrict__ bn0b,
    const float* __restrict__ bn0m, const float* __restrict__ bn0v,
    const float* __restrict__ w1, const float* __restrict__ b1,
    const float* __restrict__ bn1g, const float* __restrict__ bn1b,
    const float* __restrict__ bn1m, const float* __restrict__ bn1v,
    const float* __restrict__ w2p, const float* __restrict__ b2,
    const float* __restrict__ bn2g, const float* __restrict__ bn2b,
    const float* __restrict__ bn2m, const float* __restrict__ bn2v,
    float* __restrict__ act) {
    const int b = blockIdx.x, t = threadIdx.x;
    const float* src = (b < 512 ? inA : (b < 1024 ? inP : inN)) + (size_t)(b & 511) * NP;

    __shared__ float xpad[18 * 10];
    __shared__ float w1s[576];
    __shared__ float actA[64 * 216];  // [c][18 rows][12 cols] zero-padded
    __shared__ float s1[64], sh1[64], s2[64], sh2[64];

    for (int i = t; i < 64 * 216; i += 256) actA[i] = 0.f;
    if (t < 180) xpad[t] = 0.f;
    for (int i = t; i < 576; i += 256) w1s[i] = w1[i];
    if (t < 64) {
        float sa = bn1g[t] * rsqrtf(bn1v[t] + EPS);
        s1[t] = sa;
        sh1[t] = (b1[t] - bn1m[t]) * sa + bn1b[t];
        float sb = bn2g[t] * rsqrtf(bn2v[t] + EPS);
        s2[t] = sb;
        sh2[t] = (b2[t] - bn2m[t]) * sb + bn2b[t];
    }
    __syncthreads();
    if (t < 128) {
        float s0 = bn0g[0] * rsqrtf(bn0v[0] + EPS);
        float v = (src[t] - bn0m[0]) * s0 + bn0b[0];
        xpad[((t >> 3) + 1) * 10 + (t & 7) + 1] = v;
    }
    __syncthreads();
    // conv1 + bn1 + relu -> actA interior
#pragma unroll
    for (int q = 0; q < 32; ++q) {
        int idx = q * 256 + t;
        int c = idx >> 7, p = idx & 127;
        int r = p >> 3, cl = p & 7;
        float acc = 0.f;
#pragma unroll
        for (int kh = 0; kh < 3; ++kh)
#pragma unroll
            for (int kw = 0; kw < 3; ++kw)
                acc += w1s[c * 9 + kh * 3 + kw] * xpad[(r + kh) * 10 + cl + kw];
        float v = acc * s1[c] + sh1[c];
        actA[c * 216 + (r + 1) * 12 + cl + 1] = fmaxf(v, 0.f);
    }
    __syncthreads();
    // conv2: lane o = t&63, row-group pg = t>>6 (4 rows x 8 cols each)
    const int o = t & 63, pg = t >> 6;
    float acc[32];
#pragma unroll
    for (int i = 0; i < 32; ++i) acc[i] = 0.f;
    const float* wbase = w2p + (size_t)o * 768;  // 64*12
    for (int c = 0; c < 64; ++c) {
        float ar[6][10];
        const float* ab = actA + c * 216 + pg * 48;  // padded row pg*4, 12 cols/row
#pragma unroll
        for (int rr = 0; rr < 6; ++rr) {
            float4 v0 = *(const float4*)(ab + rr * 12);
            float4 v1 = *(const float4*)(ab + rr * 12 + 4);
            float2 v2 = *(const float2*)(ab + rr * 12 + 8);
            ar[rr][0] = v0.x; ar[rr][1] = v0.y; ar[rr][2] = v0.z; ar[rr][3] = v0.w;
            ar[rr][4] = v1.x; ar[rr][5] = v1.y; ar[rr][6] = v1.z; ar[rr][7] = v1.w;
            ar[rr][8] = v2.x; ar[rr][9] = v2.y;
        }
        float4 w0 = *(const float4*)(wbase + c * 12);
        float4 w1v = *(const float4*)(wbase + c * 12 + 4);
        float w8 = wbase[c * 12 + 8];
        float wv[9] = {w0.x, w0.y, w0.z, w0.w, w1v.x, w1v.y, w1v.z, w1v.w, w8};
#pragma unroll
        for (int kh = 0; kh < 3; ++kh)
#pragma unroll
            for (int kw = 0; kw < 3; ++kw) {
                float wk = wv[kh * 3 + kw];
#pragma unroll
                for (int rr = 0; rr < 4; ++rr)
#pragma unroll
                    for (int cc = 0; cc < 8; ++cc)
                        acc[rr * 8 + cc] += wk * ar[rr + kh][cc + kw];
            }
    }
    const float sc = s2[o], sh = sh2[o];
    float* obase = act + (size_t)b * FD + o;
#pragma unroll
    for (int rr = 0; rr < 4; ++rr)
#pragma unroll
        for (int cc = 0; cc < 8; ++cc) {
            int p = (pg * 4 + rr) * 8 + cc;
            obase[p * 64] = fmaxf(acc[rr * 8 + cc] * sc + sh, 0.f);
        }
}

// ---------------- K2: lc1 + bn3relu + lc2 + bn4relu (in-place, per position) --
__global__ __launch_bounds__(256) void k_lc(
    const float* __restrict__ w1T, const float* __restrict__ w2T,
    const float* __restrict__ bn3g, const float* __restrict__ bn3b,
    const float* __restrict__ bn3m, const float* __restrict__ bn3v,
    const float* __restrict__ bn4g, const float* __restrict__ bn4b,
    const float* __restrict__ bn4m, const float* __restrict__ bn4v,
    float* __restrict__ act) {
    const int p = blockIdx.x;
    const int b0 = blockIdx.y * 64;
    const int t = threadIdx.x;
    __shared__ float xs[64 * 68];   // [c][s]
    __shared__ float y1[64 * 68];   // [o][s]
    __shared__ float s3[64], sh3[64], s4[64], sh4[64];

    if (t < 64) {
        float sa = bn3g[t] * rsqrtf(bn3v[t] + EPS);
        s3[t] = sa; sh3[t] = bn3b[t] - bn3m[t] * sa;
        float sb = bn4g[t] * rsqrtf(bn4v[t] + EPS);
        s4[t] = sb; sh4[t] = bn4b[t] - bn4m[t] * sb;
    }
    {
        int s = t >> 2, cg = t & 3;
        const float* rp = act + (size_t)(b0 + s) * FD + p * 64 + cg * 16;
#pragma unroll
        for (int q = 0; q < 4; ++q) {
            float4 v = ((const float4*)rp)[q];
            int c = cg * 16 + q * 4;
            xs[(c + 0) * 68 + s] = v.x;
            xs[(c + 1) * 68 + s] = v.y;
            xs[(c + 2) * 68 + s] = v.z;
            xs[(c + 3) * 68 + s] = v.w;
        }
    }
    __syncthreads();
    const int ol = t & 15, sg = t >> 4;
    const int o0 = ol * 4, s0 = sg * 4;
    float a00=0,a01=0,a02=0,a03=0, a10=0,a11=0,a12=0,a13=0,
          a20=0,a21=0,a22=0,a23=0, a30=0,a31=0,a32=0,a33=0;
    {
        const float* wb = w1T + (size_t)p * 4096;
        for (int c = 0; c < 64; ++c) {
            float4 wq = *(const float4*)(wb + c * 64 + o0);
            float4 xq = *(const float4*)&xs[c * 68 + s0];
            a00 += xq.x * wq.x; a01 += xq.x * wq.y; a02 += xq.x * wq.z; a03 += xq.x * wq.w;
            a10 += xq.y * wq.x; a11 += xq.y * wq.y; a12 += xq.y * wq.z; a13 += xq.y * wq.w;
            a20 += xq.z * wq.x; a21 += xq.z * wq.y; a22 += xq.z * wq.z; a23 += xq.z * wq.w;
            a30 += xq.w * wq.x; a31 += xq.w * wq.y; a32 += xq.w * wq.z; a33 += xq.w * wq.w;
        }
    }
    // bn3+relu -> y1[o][s]
    {
        float sc0 = s3[o0], sc1 = s3[o0+1], sc2 = s3[o0+2], sc3 = s3[o0+3];
        float h0 = sh3[o0], h1 = sh3[o0+1], h2 = sh3[o0+2], h3 = sh3[o0+3];
        float4 v;
        v.x = fmaxf(a00*sc0+h0,0.f); v.y = fmaxf(a10*sc0+h0,0.f);
        v.z = fmaxf(a20*sc0+h0,0.f); v.w = fmaxf(a30*sc0+h0,0.f);
        *(float4*)&y1[(o0+0)*68 + s0] = v;
        v.x = fmaxf(a01*sc1+h1,0.f); v.y = fmaxf(a11*sc1+h1,0.f);
        v.z = fmaxf(a21*sc1+h1,0.f); v.w = fmaxf(a31*sc1+h1,0.f);
        *(float4*)&y1[(o0+1)*68 + s0] = v;
        v.x = fmaxf(a02*sc2+h2,0.f); v.y = fmaxf(a12*sc2+h2,0.f);
        v.z = fmaxf(a22*sc2+h2,0.f); v.w = fmaxf(a32*sc2+h2,0.f);
        *(float4*)&y1[(o0+2)*68 + s0] = v;
        v.x = fmaxf(a03*sc3+h3,0.f); v.y = fmaxf(a13*sc3+h3,0.f);
        v.z = fmaxf(a23*sc3+h3,0.f); v.w = fmaxf(a33*sc3+h3,0.f);
        *(float4*)&y1[(o0+3)*68 + s0] = v;
    }
    __syncthreads();
    a00=0;a01=0;a02=0;a03=0;a10=0;a11=0;a12=0;a13=0;
    a20=0;a21=0;a22=0;a23=0;a30=0;a31=0;a32=0;a33=0;
    {
        const float* wb = w2T + (size_t)p * 4096;
        for (int c = 0; c < 64; ++c) {
            float4 wq = *(const float4*)(wb + c * 64 + o0);
            float4 xq = *(const float4*)&y1[c * 68 + s0];
            a00 += xq.x * wq.x; a01 += xq.x * wq.y; a02 += xq.x * wq.z; a03 += xq.x * wq.w;
            a10 += xq.y * wq.x; a11 += xq.y * wq.y; a12 += xq.y * wq.z; a13 += xq.y * wq.w;
            a20 += xq.z * wq.x; a21 += xq.z * wq.y; a22 += xq.z * wq.z; a23 += xq.z * wq.w;
            a30 += xq.w * wq.x; a31 += xq.w * wq.y; a32 += xq.w * wq.z; a33 += xq.w * wq.w;
        }
    }
    {
        float sc0 = s4[o0], sc1 = s4[o0+1], sc2 = s4[o0+2], sc3 = s4[o0+3];
        float h0 = sh4[o0], h1 = sh4[o0+1], h2 = sh4[o0+2], h3 = sh4[o0+3];
        float4 v;
        v.x = fmaxf(a00*sc0+h0,0.f); v.y = fmaxf(a01*sc1+h1,0.f);
        v.z = fmaxf(a02*sc2+h2,0.f); v.w = fmaxf(a03*sc3+h3,0.f);
        *(float4*)(act + (size_t)(b0+s0+0)*FD + p*64 + o0) = v;
        v.x = fmaxf(a10*sc0+h0,0.f); v.y = fmaxf(a11*sc1+h1,0.f);
        v.z = fmaxf(a12*sc2+h2,0.f); v.w = fmaxf(a13*sc3+h3,0.f);
        *(float4*)(act + (size_t)(b0+s0+1)*FD + p*64 + o0) = v;
        v.x = fmaxf(a20*sc0+h0,0.f); v.y = fmaxf(a21*sc1+h1,0.f);
        v.z = fmaxf(a22*sc2+h2,0.f); v.w = fmaxf(a23*sc3+h3,0.f);
        *(float4*)(act + (size_t)(b0+s0+2)*FD + p*64 + o0) = v;
        v.x = fmaxf(a30*sc0+h0,0.f); v.y = fmaxf(a31*sc1+h1,0.f);
        v.z = fmaxf(a32*sc2+h2,0.f); v.w = fmaxf(a33*sc3+h3,0.f);
        *(float4*)(act + (size_t)(b0+s0+3)*FD + p*64 + o0) = v;
    }
}

// ---------------- tiled GEMM: out = A(M,K) * WT(K,N), fused epilogue ----------
__global__ __launch_bounds__(256) void k_gemm_full(
    const float* __restrict__ A, const float* __restrict__ Wt,
    const float* __restrict__ bias,
    const float* __restrict__ bng, const float* __restrict__ bnb,
    const float* __restrict__ bnm, const float* __restrict__ bnv,
    float* __restrict__ out, int M, int N, int K, int relu) {
    __shared__ float At[16][68];
    __shared__ float Bt[16][68];
    const int t = threadIdx.x;
    const int m0 = blockIdx.x * 64, n0 = blockIdx.y * 64;
    const int tm = t & 15, tn = t >> 4;
    float acc[4][4];
#pragma unroll
    for (int i = 0; i < 4; ++i)
#pragma unroll
        for (int j = 0; j < 4; ++j) acc[i][j] = 0.f;
    for (int k0 = 0; k0 < K; k0 += 16) {
        {
            int m = t >> 2, kl = t & 3;
            float4 v = *(const float4*)(A + (size_t)(m0 + m) * K + k0 + kl * 4);
            At[kl * 4 + 0][m] = v.x; At[kl * 4 + 1][m] = v.y;
            At[kl * 4 + 2][m] = v.z; At[kl * 4 + 3][m] = v.w;
        }
        {
            int kk = t >> 4, nl = t & 15;
            *(float4*)&Bt[kk][nl * 4] = *(const float4*)(Wt + (size_t)(k0 + kk) * N + n0 + nl * 4);
        }
        __syncthreads();
#pragma unroll
        for (int kk = 0; kk < 16; ++kk) {
            float4 a4 = *(float4*)&At[kk][tm * 4];
            float4 b4 = *(float4*)&Bt[kk][tn * 4];
            acc[0][0] += a4.x*b4.x; acc[0][1] += a4.x*b4.y; acc[0][2] += a4.x*b4.z; acc[0][3] += a4.x*b4.w;
            acc[1][0] += a4.y*b4.x; acc[1][1] += a4.y*b4.y; acc[1][2] += a4.y*b4.z; acc[1][3] += a4.y*b4.w;
            acc[2][0] += a4.z*b4.x; acc[2][1] += a4.z*b4.y; acc[2][2] += a4.z*b4.z; acc[2][3] += a4.z*b4.w;
            acc[3][0] += a4.w*b4.x; acc[3][1] += a4.w*b4.y; acc[3][2] += a4.w*b4.z; acc[3][3] += a4.w*b4.w;
        }
        __syncthreads();
    }
    float bi[4], sc[4], hh[4];
#pragma unroll
    for (int j = 0; j < 4; ++j) {
        int n = n0 + tn * 4 + j;
        bi[j] = bias[n];
        if (bng) {
            sc[j] = bng[n] * rsqrtf(bnv[n] + EPS);
            hh[j] = bnb[n] - bnm[n] * sc[j];
        }
    }
#pragma unroll
    for (int i = 0; i < 4; ++i) {
        int m = m0 + tm * 4 + i;
        float4 v;
        float r[4];
#pragma unroll
        for (int j = 0; j < 4; ++j) {
            float x = acc[i][j] + bi[j];
            if (bng) x = x * sc[j] + hh[j];
            if (relu) x = fmaxf(x, 0.f);
            r[j] = x;
        }
        v.x = r[0]; v.y = r[1]; v.z = r[2]; v.w = r[3];
        *(float4*)(out + (size_t)m * N + n0 + tn * 4) = v;
    }
}

// split-K GEMM, atomic accumulate (no epilogue)
__global__ __launch_bounds__(256) void k_gemm_atomic(
    const float* __restrict__ A, const float* __restrict__ Wt,
    float* __restrict__ out, int M, int N, int K, int kChunk) {
    __shared__ float At[16][68];
    __shared__ float Bt[16][68];
    const int t = threadIdx.x;
    const int m0 = blockIdx.x * 64, n0 = blockIdx.y * 64;
    const int kS = blockIdx.z * kChunk, kE = kS + kChunk;
    const int tm = t & 15, tn = t >> 4;
    float acc[4][4];
#pragma unroll
    for (int i = 0; i < 4; ++i)
#pragma unroll
        for (int j = 0; j < 4; ++j) acc[i][j] = 0.f;
    for (int k0 = kS; k0 < kE; k0 += 16) {
        {
            int m = t >> 2, kl = t & 3;
            float4 v = *(const float4*)(A + (size_t)(m0 + m) * K + k0 + kl * 4);
            At[kl * 4 + 0][m] = v.x; At[kl * 4 + 1][m] = v.y;
            At[kl * 4 + 2][m] = v.z; At[kl * 4 + 3][m] = v.w;
        }
        {
            int kk = t >> 4, nl = t & 15;
            *(float4*)&Bt[kk][nl * 4] = *(const float4*)(Wt + (size_t)(k0 + kk) * N + n0 + nl * 4);
        }
        __syncthreads();
#pragma unroll
        for (int kk = 0; kk < 16; ++kk) {
            float4 a4 = *(float4*)&At[kk][tm * 4];
            float4 b4 = *(float4*)&Bt[kk][tn * 4];
            acc[0][0] += a4.x*b4.x; acc[0][1] += a4.x*b4.y; acc[0][2] += a4.x*b4.z; acc[0][3] += a4.x*b4.w;
            acc[1][0] += a4.y*b4.x; acc[1][1] += a4.y*b4.y; acc[1][2] += a4.y*b4.z; acc[1][3] += a4.y*b4.w;
            acc[2][0] += a4.z*b4.x; acc[2][1] += a4.z*b4.y; acc[2][2] += a4.z*b4.z; acc[2][3] += a4.z*b4.w;
            acc[3][0] += a4.w*b4.x; acc[3][1] += a4.w*b4.y; acc[3][2] += a4.w*b4.z; acc[3][3] += a4.w*b4.w;
        }
        __syncthreads();
    }
#pragma unroll
    for (int i = 0; i < 4; ++i) {
        int m = m0 + tm * 4 + i;
#pragma unroll
        for (int j = 0; j < 4; ++j)
            atomicAdd(out + (size_t)m * N + n0 + tn * 4 + j, acc[i][j]);
    }
}

__global__ void k_zero(float* __restrict__ p, int n) {
    int i = blockIdx.x * 256 + threadIdx.x;
    if (i < n) p[i] = 0.f;
}

__global__ void k_bias_bn_relu(float* __restrict__ x, const float* __restrict__ bias,
                               const float* __restrict__ g, const float* __restrict__ b,
                               const float* __restrict__ m, const float* __restrict__ v,
                               int n, int Nmask) {
    int i = blockIdx.x * 256 + threadIdx.x;
    if (i >= n) return;
    int c = i & Nmask;
    float sc = g[c] * rsqrtf(v[c] + EPS);
    float val = (x[i] + bias[c] - m[c]) * sc + b[c];
    x[i] = fmaxf(val, 0.f);
}

extern "C" void kernel_launch(void* const* d_in, const int* in_sizes, int n_in,
                              void* d_out, int out_size, void* d_ws, size_t ws_size,
                              hipStream_t stream) {
    const float* inA    = (const float*)d_in[0];
    const float* inP    = (const float*)d_in[1];
    const float* inN    = (const float*)d_in[2];
    const float* bn0g   = (const float*)d_in[3];
    const float* bn0b   = (const float*)d_in[4];
    const float* bn0m   = (const float*)d_in[5];
    const float* bn0v   = (const float*)d_in[6];
    const float* conv1w = (const float*)d_in[7];
    const float* conv1b = (const float*)d_in[8];
    const float* bn1g   = (const float*)d_in[9];
    const float* bn1b   = (const float*)d_in[10];
    const float* bn1m   = (const float*)d_in[11];
    const float* bn1v   = (const float*)d_in[12];
    const float* conv2w = (const float*)d_in[13];
    const float* conv2b = (const float*)d_in[14];
    const float* bn2g   = (const float*)d_in[15];
    const float* bn2b   = (const float*)d_in[16];
    const float* bn2m   = (const float*)d_in[17];
    const float* bn2v   = (const float*)d_in[18];
    const float* lc1w   = (const float*)d_in[19];
    const float* bn3g   = (const float*)d_in[20];
    const float* bn3b   = (const float*)d_in[21];
    const float* bn3m   = (const float*)d_in[22];
    const float* bn3v   = (const float*)d_in[23];
    const float* lc2w   = (const float*)d_in[24];
    const float* bn4g   = (const float*)d_in[25];
    const float* bn4b   = (const float*)d_in[26];
    const float* bn4m   = (const float*)d_in[27];
    const float* bn4v   = (const float*)d_in[28];
    const float* fc1w   = (const float*)d_in[29];
    const float* fc1b   = (const float*)d_in[30];
    const float* bnf1g  = (const float*)d_in[31];
    const float* bnf1b  = (const float*)d_in[32];
    const float* bnf1m  = (const float*)d_in[33];
    const float* bnf1v  = (const float*)d_in[34];
    const float* fc2w   = (const float*)d_in[35];
    const float* fc2b   = (const float*)d_in[36];
    const float* bnf2g  = (const float*)d_in[37];
    const float* bnf2b  = (const float*)d_in[38];
    const float* bnf2m  = (const float*)d_in[39];
    const float* bnf2v  = (const float*)d_in[40];
    const float* fc3w   = (const float*)d_in[41];
    const float* fc3b   = (const float*)d_in[42];
    const float* bnf3g  = (const float*)d_in[43];
    const float* bnf3b  = (const float*)d_in[44];
    const float* bnf3m  = (const float*)d_in[45];
    const float* bnf3v  = (const float*)d_in[46];
    const float* outw   = (const float*)d_in[47];
    const float* outb   = (const float*)d_in[48];

    float* ws = (float*)d_ws;
    float* wsW2P = ws;                     // 49152
    float* wsLC1 = wsW2P + 49152;          // 524288
    float* wsLC2 = wsLC1 + 524288;         // 524288
    float* wsFC1 = wsLC2 + 524288;         // 4194304
    float* wsFC2 = wsFC1 + 4194304;        // 262144
    float* wsFC3 = wsFC2 + 262144;         // 65536
    float* wsOUT = wsFC3 + 65536;          // 16384
    float* act1  = wsOUT + 16384;          // 1536*8192 = 12582912
    float* act3  = act1 + 12582912;        // 1536*512
    float* act4  = act3 + 786432;          // 1536*512
    float* act5  = act4 + 786432;          // 1536*128

    // ---- weight prep ----
    k_pack_w2<<<192, 256, 0, stream>>>(conv2w, wsW2P);
    k_t_lc<<<dim3(64, 2), 256, 0, stream>>>(lc1w, lc2w, wsLC1, wsLC2);
    k_t_w<true><<<dim3(128, 8), 256, 0, stream>>>(fc1w, wsFC1, 512, 8192);
    k_t_w<false><<<dim3(8, 8), 256, 0, stream>>>(fc2w, wsFC2, 512, 512);
    k_t_w<false><<<dim3(8, 2), 256, 0, stream>>>(fc3w, wsFC3, 128, 512);
    k_t_w<false><<<dim3(2, 2), 256, 0, stream>>>(outw, wsOUT, 128, 128);

    // ---- conv stage ----
    k_conv<<<1536, 256, 0, stream>>>(inA, inP, inN,
        bn0g, bn0b, bn0m, bn0v, conv1w, conv1b, bn1g, bn1b, bn1m, bn1v,
        wsW2P, conv2b, bn2g, bn2b, bn2m, bn2v, act1);

    // ---- locally connected (in place on act1) ----
    k_lc<<<dim3(128, 24), 256, 0, stream>>>(wsLC1, wsLC2,
        bn3g, bn3b, bn3m, bn3v, bn4g, bn4b, bn4m, bn4v, act1);

    // ---- fc1 (split-K atomic) + epilogue ----
    k_zero<<<(786432 + 255) / 256, 256, 0, stream>>>(act3, 786432);
    k_gemm_atomic<<<dim3(24, 8, 4), 256, 0, stream>>>(act1, wsFC1, act3, 1536, 512, 8192, 2048);
    k_bias_bn_relu<<<(786432 + 255) / 256, 256, 0, stream>>>(act3, fc1b,
        bnf1g, bnf1b, bnf1m, bnf1v, 786432, 511);

    // ---- fc2 / fc3 / out ----
    k_gemm_full<<<dim3(24, 8), 256, 0, stream>>>(act3, wsFC2, fc2b,
        bnf2g, bnf2b, bnf2m, bnf2v, act4, 1536, 512, 512, 1);
    k_gemm_full<<<dim3(24, 2), 256, 0, stream>>>(act4, wsFC3, fc3b,
        bnf3g, bnf3b, bnf3m, bnf3v, act5, 1536, 128, 512, 1);
    k_gemm_full<<<dim3(24, 2), 256, 0, stream>>>(act5, wsOUT, outb,
        nullptr, nullptr, nullptr, nullptr, (float*)d_out, 1536, 128, 128, 0);
}

// Round 2
// 349.631 us; speedup vs baseline: 1.9866x; 1.9866x over previous
//
#include <hip/hip_runtime.h>
#include <math.h>

#define EPS 1e-5f
#define FD 8192

typedef __attribute__((ext_vector_type(8))) __bf16 bf16x8;
typedef __attribute__((ext_vector_type(4))) float f32x4;

static __device__ __forceinline__ f32x4 mfma16(bf16x8 a, bf16x8 b, f32x4 c) {
    return __builtin_amdgcn_mfma_f32_16x16x32_bf16(a, b, c, 0, 0, 0);
}

// ================= prep: conv1 weights -> B-fragment order ===================
// w1frag[(w*64+lane)*8 + j] = B1[k=q*8+j][o=w*16+(lane&15)], k<9 real else 0
__global__ void k_prep_w1frag(const float* __restrict__ w1, __bf16* __restrict__ out) {
    const int t = threadIdx.x;          // 256
    const int lane = t & 63, w = t >> 6;
    const int q = lane >> 4, li = lane & 15;
    const int o = w * 16 + li;
    bf16x8 v;
#pragma unroll
    for (int j = 0; j < 8; ++j) {
        int k = q * 8 + j;
        v[j] = (k < 9) ? (__bf16)w1[o * 9 + k] : (__bf16)0.0f;
    }
    *(bf16x8*)(out + t * 8) = v;
}

// ============== prep: conv2 weights -> B-fragment order per (tap,chunk,w) =====
// out[(((tap*2+chunk)*4+w)*64+lane)*8 + j] = w2[o=w*16+(lane&15)][c=chunk*32+q*8+j][tap]
__global__ void k_prep_w2frag(const float* __restrict__ w2, __bf16* __restrict__ out) {
    const int id = blockIdx.x * 256 + threadIdx.x;  // 18*256 = 4608
    const int lane = id & 63;
    const int w = (id >> 6) & 3;
    const int chunk = (id >> 8) & 1;
    const int tap = id >> 9;
    const int q = lane >> 4, li = lane & 15;
    const int o = w * 16 + li;
    const int c0 = chunk * 32 + q * 8;
    bf16x8 v;
#pragma unroll
    for (int j = 0; j < 8; ++j)
        v[j] = (__bf16)w2[(o * 64 + c0 + j) * 9 + tap];
    *(bf16x8*)(out + (size_t)id * 8) = v;
}

// ============== prep: lc weights -> B-fragment order per (p,chunk,w) ==========
// out[(((p*2+chunk)*4+w)*64+lane)*8 + j] = w_lc[o=w*16+(lane&15)][c=chunk*32+q*8+j][p]
__global__ void k_prep_lcfrag(const float* __restrict__ lc1, const float* __restrict__ lc2,
                              __bf16* __restrict__ o1, __bf16* __restrict__ o2) {
    const int bx = blockIdx.x;          // 512 blocks
    const int pg = bx & 31, w = (bx >> 5) & 3, chunk = (bx >> 7) & 1, layer = bx >> 8;
    const int t = threadIdx.x;
    const int lane = t & 63, pi = t >> 6;
    const int p = pg * 4 + pi;
    const int q = lane >> 4, li = lane & 15;
    const int o = w * 16 + li;
    const int c0 = chunk * 32 + q * 8;
    const float* src = layer ? lc2 : lc1;
    __bf16* dst = layer ? o2 : o1;
    bf16x8 v;
#pragma unroll
    for (int j = 0; j < 8; ++j)
        v[j] = (__bf16)src[(size_t)(o * 64 + c0 + j) * 128 + p];
    *(bf16x8*)(dst + ((size_t)((p * 2 + chunk) * 4 + w) * 64 + lane) * 8) = v;
}

// ===== prep: fc1 weights -> bf16 [n][kA] with kA = p*64+c (korig = c*128+p) ===
__global__ void k_prep_fc1w(const float* __restrict__ fw, __bf16* __restrict__ out) {
    const int n = blockIdx.x;           // 512
    const int t = threadIdx.x;
#pragma unroll
    for (int i = 0; i < 32; ++i) {
        int kA = i * 256 + t;
        int korig = ((kA & 63) << 7) | (kA >> 6);
        out[(size_t)n * 8192 + kA] = (__bf16)fw[(size_t)n * 8192 + korig];
    }
}

// ----- fp32 weight transpose (R,C)->(C,R) for fc2/fc3/out (unchanged) --------
__global__ __launch_bounds__(256) void k_t_w(const float* __restrict__ in,
                                             float* __restrict__ out, int R, int C) {
    __shared__ float tl[64][68];
    const int t = threadIdx.x;
    const int c0 = blockIdx.x * 64, r0 = blockIdx.y * 64;
    {
        int kl = t & 15, rr = t >> 4;
#pragma unroll
        for (int pass = 0; pass < 4; ++pass) {
            int r = rr + pass * 16;
            float4 v = *(const float4*)(in + (size_t)(r0 + r) * C + c0 + kl * 4);
            *(float4*)&tl[r][kl * 4] = v;
        }
    }
    __syncthreads();
    {
        int jl = t & 15, kk = t >> 4;
#pragma unroll
        for (int pass = 0; pass < 4; ++pass) {
            int cc = kk + pass * 16;
            float4 v = make_float4(tl[jl * 4 + 0][cc], tl[jl * 4 + 1][cc],
                                   tl[jl * 4 + 2][cc], tl[jl * 4 + 3][cc]);
            *(float4*)(out + (size_t)(c0 + cc) * R + r0 + jl * 4) = v;
        }
    }
}

// ========== K1: bn0 + conv1(MFMA) + bn1relu + conv2(MFMA) + bn2relu ==========
// one block per sample; writes act (bf16) layout [b][p*64 + c]
__global__ __launch_bounds__(256) void k_conv_mfma(
    const float* __restrict__ inA, const float* __restrict__ inP, const float* __restrict__ inN,
    const float* __restrict__ bn0g, const float* __restrict__ bn0b,
    const float* __restrict__ bn0m, const float* __restrict__ bn0v,
    const __bf16* __restrict__ w1frag, const float* __restrict__ b1,
    const float* __restrict__ bn1g, const float* __restrict__ bn1b,
    const float* __restrict__ bn1m, const float* __restrict__ bn1v,
    const __bf16* __restrict__ w2frag, const float* __restrict__ b2,
    const float* __restrict__ bn2g, const float* __restrict__ bn2b,
    const float* __restrict__ bn2m, const float* __restrict__ bn2v,
    __bf16* __restrict__ act) {
    const int b = blockIdx.x, t = threadIdx.x;
    const int lane = t & 63, w = t >> 6;
    const int q = lane >> 4, li = lane & 15;
    const int n0 = w * 16;
    const float* src = (b < 512 ? inA : (b < 1024 ? inP : inN)) + (size_t)(b & 511) * 128;

    __shared__ __align__(16) float xpad[180];            // 18x10 padded bn0 input
    __shared__ __align__(16) __bf16 A1[128 * 40];        // conv1 im2col (K=32, stride 40)
    __shared__ __align__(16) __bf16 Xp[18 * 12 * 72];    // conv1 out padded, c-inner str 72
    __shared__ float s1[64], sh1[64], s2[64], sh2[64];

    // --- fragment loads from global (hoisted; latency hidden behind phases) ---
    bf16x8 w1f = *(const bf16x8*)(w1frag + (size_t)(w * 64 + lane) * 8);
    bf16x8 w2f[18];
#pragma unroll
    for (int tap = 0; tap < 9; ++tap)
#pragma unroll
        for (int ch = 0; ch < 2; ++ch)
            w2f[tap * 2 + ch] = *(const bf16x8*)(w2frag +
                ((size_t)((tap * 2 + ch) * 4 + w) * 64 + lane) * 8);

    // S0: zero LDS + bn constants
    {
        int* xz = (int*)Xp;                               // 7776 ints
        for (int i = t; i < 7776; i += 256) xz[i] = 0;
        if (t < 180) xpad[t] = 0.f;
        if (t < 64) {
            float sa = bn1g[t] * rsqrtf(bn1v[t] + EPS);
            s1[t] = sa;
            sh1[t] = (b1[t] - bn1m[t]) * sa + bn1b[t];
            float sb = bn2g[t] * rsqrtf(bn2v[t] + EPS);
            s2[t] = sb;
            sh2[t] = (b2[t] - bn2m[t]) * sb + bn2b[t];
        }
    }
    __syncthreads();
    // S1: bn0 + pad input
    if (t < 128) {
        float s0 = bn0g[0] * rsqrtf(bn0v[0] + EPS);
        float v = (src[t] - bn0m[0]) * s0 + bn0b[0];
        xpad[((t >> 3) + 1) * 10 + (t & 7) + 1] = v;
    }
    __syncthreads();
    // S2: build conv1 im2col A1[p][k], k = kh*3+kw (<9), zeros to 31
    {
        int p = t >> 1, jh = (t & 1) * 16;
        int r = p >> 3, cl = p & 7;
#pragma unroll
        for (int jj = 0; jj < 16; ++jj) {
            int j = jh + jj;
            float v = 0.f;
            if (j < 9) v = xpad[(r + j / 3) * 10 + cl + (j % 3)];
            A1[p * 40 + j] = (__bf16)v;
        }
    }
    __syncthreads();
    // S3: conv1 MFMA (8 M-tiles), bn1+relu, write Xp interior (c-inner bf16)
    {
        const float sco = s1[n0 + li], sho = sh1[n0 + li];
        const int o = n0 + li;
#pragma unroll
        for (int m = 0; m < 8; ++m) {
            bf16x8 a = *(const bf16x8*)&A1[(m * 16 + li) * 40 + q * 8];
            f32x4 z = {0.f, 0.f, 0.f, 0.f};
            f32x4 d = mfma16(a, w1f, z);
#pragma unroll
            for (int r = 0; r < 4; ++r) {
                int p = m * 16 + q * 4 + r;
                float v = fmaxf(d[r] * sco + sho, 0.f);
                Xp[(((p >> 3) + 1) * 12 + (p & 7) + 1) * 72 + o] = (__bf16)v;
            }
        }
    }
    __syncthreads();
    // S4: conv2 implicit GEMM: 9 taps x K=64, 2 M-tiles in flight
    {
        const float sco = s2[n0 + li], sho = sh2[n0 + li];
        const int o = n0 + li;
        const int cl = li & 7;
#pragma unroll
        for (int mp = 0; mp < 4; ++mp) {
            const int m0t = mp * 2;
            const int r0 = m0t * 2 + (li >> 3);
            const int base0 = (r0 * 12 + cl) * 72 + q * 8;
            const int base1 = base0 + 1728;               // +2 rows
            f32x4 acc0 = {0.f, 0.f, 0.f, 0.f};
            f32x4 acc1 = {0.f, 0.f, 0.f, 0.f};
#pragma unroll
            for (int tap = 0; tap < 9; ++tap) {
                const int tofs = ((tap / 3) * 12 + (tap % 3)) * 72;
#pragma unroll
                for (int ch = 0; ch < 2; ++ch) {
                    bf16x8 a0 = *(const bf16x8*)&Xp[base0 + tofs + ch * 32];
                    bf16x8 a1 = *(const bf16x8*)&Xp[base1 + tofs + ch * 32];
                    acc0 = mfma16(a0, w2f[tap * 2 + ch], acc0);
                    acc1 = mfma16(a1, w2f[tap * 2 + ch], acc1);
                }
            }
            __bf16* ob = act + (size_t)b * FD + o;
#pragma unroll
            for (int r = 0; r < 4; ++r) {
                int p0 = m0t * 16 + q * 4 + r;
                ob[p0 * 64] = (__bf16)fmaxf(acc0[r] * sco + sho, 0.f);
                ob[(p0 + 16) * 64] = (__bf16)fmaxf(acc1[r] * sco + sho, 0.f);
            }
        }
    }
}

// ========== K2: lc1 + bn3relu + lc2 + bn4relu (MFMA, in-place) ===============
__global__ __launch_bounds__(256) void k_lc_mfma(
    const __bf16* __restrict__ lc1frag, const __bf16* __restrict__ lc2frag,
    const float* __restrict__ bn3g, const float* __restrict__ bn3b,
    const float* __restrict__ bn3m, const float* __restrict__ bn3v,
    const float* __restrict__ bn4g, const float* __restrict__ bn4b,
    const float* __restrict__ bn4m, const float* __restrict__ bn4v,
    __bf16* __restrict__ act) {
    const int p = blockIdx.x;
    const int b0 = blockIdx.y * 64;
    const int t = threadIdx.x;
    const int lane = t & 63, w = t >> 6;
    const int q = lane >> 4, li = lane & 15;
    const int n0 = w * 16;

    __shared__ __align__(16) __bf16 xs[64 * 72];
    __shared__ __align__(16) __bf16 ys[64 * 72];
    __shared__ float s3[64], sh3[64], s4[64], sh4[64];

    if (t < 64) {
        float sa = bn3g[t] * rsqrtf(bn3v[t] + EPS);
        s3[t] = sa; sh3[t] = bn3b[t] - bn3m[t] * sa;
        float sb = bn4g[t] * rsqrtf(bn4v[t] + EPS);
        s4[t] = sb; sh4[t] = bn4b[t] - bn4m[t] * sb;
    }
    {   // stage X[b][c] for 64 samples
        int s = t >> 2, cg = t & 3;
        const __bf16* rp = act + (size_t)(b0 + s) * FD + p * 64 + cg * 16;
        *(bf16x8*)&xs[s * 72 + cg * 16] = *(const bf16x8*)rp;
        *(bf16x8*)&xs[s * 72 + cg * 16 + 8] = *(const bf16x8*)(rp + 8);
    }
    bf16x8 w1a = *(const bf16x8*)(lc1frag + ((size_t)((p * 2 + 0) * 4 + w) * 64 + lane) * 8);
    bf16x8 w1b = *(const bf16x8*)(lc1frag + ((size_t)((p * 2 + 1) * 4 + w) * 64 + lane) * 8);
    bf16x8 w2a = *(const bf16x8*)(lc2frag + ((size_t)((p * 2 + 0) * 4 + w) * 64 + lane) * 8);
    bf16x8 w2b = *(const bf16x8*)(lc2frag + ((size_t)((p * 2 + 1) * 4 + w) * 64 + lane) * 8);
    __syncthreads();
    {   // layer 1
        const float sco = s3[n0 + li], sho = sh3[n0 + li];
#pragma unroll
        for (int m = 0; m < 4; ++m) {
            bf16x8 a0 = *(const bf16x8*)&xs[(m * 16 + li) * 72 + q * 8];
            bf16x8 a1 = *(const bf16x8*)&xs[(m * 16 + li) * 72 + 32 + q * 8];
            f32x4 acc = {0.f, 0.f, 0.f, 0.f};
            acc = mfma16(a0, w1a, acc);
            acc = mfma16(a1, w1b, acc);
#pragma unroll
            for (int r = 0; r < 4; ++r) {
                int bl = m * 16 + q * 4 + r;
                ys[bl * 72 + n0 + li] = (__bf16)fmaxf(acc[r] * sco + sho, 0.f);
            }
        }
    }
    __syncthreads();
    {   // layer 2
        const float sco = s4[n0 + li], sho = sh4[n0 + li];
#pragma unroll
        for (int m = 0; m < 4; ++m) {
            bf16x8 a0 = *(const bf16x8*)&ys[(m * 16 + li) * 72 + q * 8];
            bf16x8 a1 = *(const bf16x8*)&ys[(m * 16 + li) * 72 + 32 + q * 8];
            f32x4 acc = {0.f, 0.f, 0.f, 0.f};
            acc = mfma16(a0, w2a, acc);
            acc = mfma16(a1, w2b, acc);
#pragma unroll
            for (int r = 0; r < 4; ++r) {
                int bl = m * 16 + q * 4 + r;
                act[(size_t)(b0 + bl) * FD + p * 64 + n0 + li] =
                    (__bf16)fmaxf(acc[r] * sco + sho, 0.f);
            }
        }
    }
}

// ========== K3: fc1 MFMA 128x128 tile, split-K 4, fp32 partials ==============
__global__ __launch_bounds__(256) void k_fc1_mfma(
    const __bf16* __restrict__ A, const __bf16* __restrict__ Wb,
    float* __restrict__ part) {
    const int t = threadIdx.x;
    const int lane = t & 63, w = t >> 6;
    const int q = lane >> 4, li = lane & 15;
    const int m0 = blockIdx.x * 128, n0 = blockIdx.y * 128;
    const int k0 = blockIdx.z * 2048;
    const int wm = (w & 1) * 64, wn = (w >> 1) * 64;

    __shared__ __align__(16) __bf16 As[128 * 40];
    __shared__ __align__(16) __bf16 Bs[128 * 40];

    f32x4 acc[4][4];
#pragma unroll
    for (int i = 0; i < 4; ++i)
#pragma unroll
        for (int j = 0; j < 4; ++j) acc[i][j] = (f32x4){0.f, 0.f, 0.f, 0.f};

    const int row = t >> 1, half = t & 1;
    const __bf16* Ag = A + (size_t)(m0 + row) * 8192 + k0 + half * 16;
    const __bf16* Bg = Wb + (size_t)(n0 + row) * 8192 + k0 + half * 16;

    for (int step = 0; step < 64; ++step) {
        bf16x8 a0 = *(const bf16x8*)Ag;
        bf16x8 a1 = *(const bf16x8*)(Ag + 8);
        bf16x8 b0 = *(const bf16x8*)Bg;
        bf16x8 b1 = *(const bf16x8*)(Bg + 8);
        *(bf16x8*)&As[row * 40 + half * 16] = a0;
        *(bf16x8*)&As[row * 40 + half * 16 + 8] = a1;
        *(bf16x8*)&Bs[row * 40 + half * 16] = b0;
        *(bf16x8*)&Bs[row * 40 + half * 16 + 8] = b1;
        __syncthreads();
        bf16x8 af[4], bf[4];
#pragma unroll
        for (int i = 0; i < 4; ++i)
            af[i] = *(const bf16x8*)&As[(wm + i * 16 + li) * 40 + q * 8];
#pragma unroll
        for (int j = 0; j < 4; ++j)
            bf[j] = *(const bf16x8*)&Bs[(wn + j * 16 + li) * 40 + q * 8];
#pragma unroll
        for (int i = 0; i < 4; ++i)
#pragma unroll
            for (int j = 0; j < 4; ++j)
                acc[i][j] = mfma16(af[i], bf[j], acc[i][j]);
        __syncthreads();
        Ag += 32;
        Bg += 32;
    }
    float* pp = part + (size_t)blockIdx.z * 786432;
#pragma unroll
    for (int i = 0; i < 4; ++i) {
#pragma unroll
        for (int r = 0; r < 4; ++r) {
            int m = m0 + wm + i * 16 + q * 4 + r;
#pragma unroll
            for (int j = 0; j < 4; ++j) {
                int n = n0 + wn + j * 16 + li;
                pp[(size_t)m * 512 + n] = acc[i][j][r];
            }
        }
    }
}

// reduce 4 partials + bias + bn + relu -> fp32 act3
__global__ void k_fc1_reduce(const float* __restrict__ part, const float* __restrict__ bias,
                             const float* __restrict__ g, const float* __restrict__ bb,
                             const float* __restrict__ mm, const float* __restrict__ vv,
                             float* __restrict__ out) {
    int gi = blockIdx.x * 256 + threadIdx.x;   // 196608 float4s
    size_t off = (size_t)gi * 4;
    float4 s = *(const float4*)(part + off);
    float4 s1 = *(const float4*)(part + 786432 + off);
    float4 s2 = *(const float4*)(part + 2 * 786432 + off);
    float4 s3 = *(const float4*)(part + 3 * 786432 + off);
    s.x += s1.x + s2.x + s3.x; s.y += s1.y + s2.y + s3.y;
    s.z += s1.z + s2.z + s3.z; s.w += s1.w + s2.w + s3.w;
    int n = (gi & 127) * 4;
    float r[4] = {s.x, s.y, s.z, s.w};
    float4 o;
#pragma unroll
    for (int j = 0; j < 4; ++j) {
        float sc = g[n + j] * rsqrtf(vv[n + j] + EPS);
        float x = (r[j] + bias[n + j] - mm[n + j]) * sc + bb[n + j];
        r[j] = fmaxf(x, 0.f);
    }
    o.x = r[0]; o.y = r[1]; o.z = r[2]; o.w = r[3];
    *(float4*)(out + off) = o;
}

// ---------------- fp32 tiled GEMM with fused epilogue (fc2/fc3/out) ----------
__global__ __launch_bounds__(256) void k_gemm_full(
    const float* __restrict__ A, const float* __restrict__ Wt,
    const float* __restrict__ bias,
    const float* __restrict__ bng, const float* __restrict__ bnb,
    const float* __restrict__ bnm, const float* __restrict__ bnv,
    float* __restrict__ out, int M, int N, int K, int relu) {
    __shared__ float At[16][68];
    __shared__ float Bt[16][68];
    const int t = threadIdx.x;
    const int m0 = blockIdx.x * 64, n0 = blockIdx.y * 64;
    const int tm = t & 15, tn = t >> 4;
    float acc[4][4];
#pragma unroll
    for (int i = 0; i < 4; ++i)
#pragma unroll
        for (int j = 0; j < 4; ++j) acc[i][j] = 0.f;
    for (int k0 = 0; k0 < K; k0 += 16) {
        {
            int m = t >> 2, kl = t & 3;
            float4 v = *(const float4*)(A + (size_t)(m0 + m) * K + k0 + kl * 4);
            At[kl * 4 + 0][m] = v.x; At[kl * 4 + 1][m] = v.y;
            At[kl * 4 + 2][m] = v.z; At[kl * 4 + 3][m] = v.w;
        }
        {
            int kk = t >> 4, nl = t & 15;
            *(float4*)&Bt[kk][nl * 4] = *(const float4*)(Wt + (size_t)(k0 + kk) * N + n0 + nl * 4);
        }
        __syncthreads();
#pragma unroll
        for (int kk = 0; kk < 16; ++kk) {
            float4 a4 = *(float4*)&At[kk][tm * 4];
            float4 b4 = *(float4*)&Bt[kk][tn * 4];
            acc[0][0] += a4.x*b4.x; acc[0][1] += a4.x*b4.y; acc[0][2] += a4.x*b4.z; acc[0][3] += a4.x*b4.w;
            acc[1][0] += a4.y*b4.x; acc[1][1] += a4.y*b4.y; acc[1][2] += a4.y*b4.z; acc[1][3] += a4.y*b4.w;
            acc[2][0] += a4.z*b4.x; acc[2][1] += a4.z*b4.y; acc[2][2] += a4.z*b4.z; acc[2][3] += a4.z*b4.w;
            acc[3][0] += a4.w*b4.x; acc[3][1] += a4.w*b4.y; acc[3][2] += a4.w*b4.z; acc[3][3] += a4.w*b4.w;
        }
        __syncthreads();
    }
    float bi[4], sc[4], hh[4];
#pragma unroll
    for (int j = 0; j < 4; ++j) {
        int n = n0 + tn * 4 + j;
        bi[j] = bias[n];
        if (bng) {
            sc[j] = bng[n] * rsqrtf(bnv[n] + EPS);
            hh[j] = bnb[n] - bnm[n] * sc[j];
        }
    }
#pragma unroll
    for (int i = 0; i < 4; ++i) {
        int m = m0 + tm * 4 + i;
        float4 v;
        float r[4];
#pragma unroll
        for (int j = 0; j < 4; ++j) {
            float x = acc[i][j] + bi[j];
            if (bng) x = x * sc[j] + hh[j];
            if (relu) x = fmaxf(x, 0.f);
            r[j] = x;
        }
        v.x = r[0]; v.y = r[1]; v.z = r[2]; v.w = r[3];
        *(float4*)(out + (size_t)m * N + n0 + tn * 4) = v;
    }
}

extern "C" void kernel_launch(void* const* d_in, const int* in_sizes, int n_in,
                              void* d_out, int out_size, void* d_ws, size_t ws_size,
                              hipStream_t stream) {
    const float* inA    = (const float*)d_in[0];
    const float* inP    = (const float*)d_in[1];
    const float* inN    = (const float*)d_in[2];
    const float* bn0g   = (const float*)d_in[3];
    const float* bn0b   = (const float*)d_in[4];
    const float* bn0m   = (const float*)d_in[5];
    const float* bn0v   = (const float*)d_in[6];
    const float* conv1w = (const float*)d_in[7];
    const float* conv1b = (const float*)d_in[8];
    const float* bn1g   = (const float*)d_in[9];
    const float* bn1b   = (const float*)d_in[10];
    const float* bn1m   = (const float*)d_in[11];
    const float* bn1v   = (const float*)d_in[12];
    const float* conv2w = (const float*)d_in[13];
    const float* conv2b = (const float*)d_in[14];
    const float* bn2g   = (const float*)d_in[15];
    const float* bn2b   = (const float*)d_in[16];
    const float* bn2m   = (const float*)d_in[17];
    const float* bn2v   = (const float*)d_in[18];
    const float* lc1w   = (const float*)d_in[19];
    const float* bn3g   = (const float*)d_in[20];
    const float* bn3b   = (const float*)d_in[21];
    const float* bn3m   = (const float*)d_in[22];
    const float* bn3v   = (const float*)d_in[23];
    const float* lc2w   = (const float*)d_in[24];
    const float* bn4g   = (const float*)d_in[25];
    const float* bn4b   = (const float*)d_in[26];
    const float* bn4m   = (const float*)d_in[27];
    const float* bn4v   = (const float*)d_in[28];
    const float* fc1w   = (const float*)d_in[29];
    const float* fc1b   = (const float*)d_in[30];
    const float* bnf1g  = (const float*)d_in[31];
    const float* bnf1b  = (const float*)d_in[32];
    const float* bnf1m  = (const float*)d_in[33];
    const float* bnf1v  = (const float*)d_in[34];
    const float* fc2w   = (const float*)d_in[35];
    const float* fc2b   = (const float*)d_in[36];
    const float* bnf2g  = (const float*)d_in[37];
    const float* bnf2b  = (const float*)d_in[38];
    const float* bnf2m  = (const float*)d_in[39];
    const float* bnf2v  = (const float*)d_in[40];
    const float* fc3w   = (const float*)d_in[41];
    const float* fc3b   = (const float*)d_in[42];
    const float* bnf3g  = (const float*)d_in[43];
    const float* bnf3b  = (const float*)d_in[44];
    const float* bnf3m  = (const float*)d_in[45];
    const float* bnf3v  = (const float*)d_in[46];
    const float* outw   = (const float*)d_in[47];
    const float* outb   = (const float*)d_in[48];

    char* wsb = (char*)d_ws;
    __bf16* w1frag  = (__bf16*)wsb;                        // 2048 el
    __bf16* w2frag  = (__bf16*)(wsb + 4096);               // 36864 el
    __bf16* lc1frag = (__bf16*)(wsb + 81920);              // 524288 el
    __bf16* lc2frag = lc1frag + 524288;
    __bf16* fc1Wb   = lc2frag + 524288;                    // 4194304 el
    __bf16* act     = fc1Wb + 4194304;                     // 12582912 el (1536x8192)
    float*  part    = (float*)(act + 12582912);            // 4 x 786432
    float*  act3    = part + 4 * 786432;
    float*  wsFC2   = act3 + 786432;                       // 262144
    float*  act4    = wsFC2 + 262144;
    float*  wsFC3   = act4 + 786432;                       // 65536
    float*  act5    = wsFC3 + 65536;                       // 196608
    float*  wsOUT   = act5 + 196608;                       // 16384

    // ---- weight prep ----
    k_prep_w1frag<<<1, 256, 0, stream>>>(conv1w, w1frag);
    k_prep_w2frag<<<18, 256, 0, stream>>>(conv2w, w2frag);
    k_prep_lcfrag<<<512, 256, 0, stream>>>(lc1w, lc2w, lc1frag, lc2frag);
    k_prep_fc1w<<<512, 256, 0, stream>>>(fc1w, fc1Wb);
    k_t_w<<<dim3(8, 8), 256, 0, stream>>>(fc2w, wsFC2, 512, 512);
    k_t_w<<<dim3(8, 2), 256, 0, stream>>>(fc3w, wsFC3, 128, 512);
    k_t_w<<<dim3(2, 2), 256, 0, stream>>>(outw, wsOUT, 128, 128);

    // ---- conv stage (MFMA) ----
    k_conv_mfma<<<1536, 256, 0, stream>>>(inA, inP, inN,
        bn0g, bn0b, bn0m, bn0v, w1frag, conv1b, bn1g, bn1b, bn1m, bn1v,
        w2frag, conv2b, bn2g, bn2b, bn2m, bn2v, act);

    // ---- locally connected (MFMA, in place) ----
    k_lc_mfma<<<dim3(128, 24), 256, 0, stream>>>(lc1frag, lc2frag,
        bn3g, bn3b, bn3m, bn3v, bn4g, bn4b, bn4m, bn4v, act);

    // ---- fc1 (MFMA split-K) + reduce ----
    k_fc1_mfma<<<dim3(12, 4, 4), 256, 0, stream>>>(act, fc1Wb, part);
    k_fc1_reduce<<<768, 256, 0, stream>>>(part, fc1b, bnf1g, bnf1b, bnf1m, bnf1v, act3);

    // ---- fc2 / fc3 / out (fp32) ----
    k_gemm_full<<<dim3(24, 8), 256, 0, stream>>>(act3, wsFC2, fc2b,
        bnf2g, bnf2b, bnf2m, bnf2v, act4, 1536, 512, 512, 1);
    k_gemm_full<<<dim3(24, 2), 256, 0, stream>>>(act4, wsFC3, fc3b,
        bnf3g, bnf3b, bnf3m, bnf3v, act5, 1536, 128, 512, 1);
    k_gemm_full<<<dim3(24, 2), 256, 0, stream>>>(act5, wsOUT, outb,
        nullptr, nullptr, nullptr, nullptr, (float*)d_out, 1536, 128, 128, 0);
}

// Round 3
// 262.245 us; speedup vs baseline: 2.6486x; 1.3332x over previous
//
#include <hip/hip_runtime.h>
#include <math.h>

#define EPS 1e-5f
#define FD 8192

typedef __attribute__((ext_vector_type(8))) __bf16 bf16x8;
typedef __attribute__((ext_vector_type(4))) float f32x4;

static __device__ __forceinline__ f32x4 mfma16(bf16x8 a, bf16x8 b, f32x4 c) {
    return __builtin_amdgcn_mfma_f32_16x16x32_bf16(a, b, c, 0, 0, 0);
}

// ================= prep: conv1 weights -> B-fragment order ===================
__global__ void k_prep_w1frag(const float* __restrict__ w1, __bf16* __restrict__ out) {
    const int t = threadIdx.x;          // 256
    const int lane = t & 63, w = t >> 6;
    const int q = lane >> 4, li = lane & 15;
    const int o = w * 16 + li;
    bf16x8 v;
#pragma unroll
    for (int j = 0; j < 8; ++j) {
        int k = q * 8 + j;
        v[j] = (k < 9) ? (__bf16)w1[o * 9 + k] : (__bf16)0.0f;
    }
    *(bf16x8*)(out + t * 8) = v;
}

// ============== prep: conv2 weights -> B-fragment order per (tap,chunk,w) =====
__global__ void k_prep_w2frag(const float* __restrict__ w2, __bf16* __restrict__ out) {
    const int id = blockIdx.x * 256 + threadIdx.x;  // 18*256 = 4608
    const int lane = id & 63;
    const int w = (id >> 6) & 3;
    const int chunk = (id >> 8) & 1;
    const int tap = id >> 9;
    const int q = lane >> 4, li = lane & 15;
    const int o = w * 16 + li;
    const int c0 = chunk * 32 + q * 8;
    bf16x8 v;
#pragma unroll
    for (int j = 0; j < 8; ++j)
        v[j] = (__bf16)w2[(o * 64 + c0 + j) * 9 + tap];
    *(bf16x8*)(out + (size_t)id * 8) = v;
}

// ====== prep: lc weights -> frag order, coalesced via LDS (block per (layer,o))
// dst[(((p*2+chunk)*4+wo)*64 + q*16+lo)*8 + j] = src[(o*64 + chunk*32+q*8+j)*128 + p]
__global__ __launch_bounds__(256) void k_prep_lcT(const float* __restrict__ lc1,
                                                  const float* __restrict__ lc2,
                                                  __bf16* __restrict__ o1,
                                                  __bf16* __restrict__ o2) {
    const int bx = blockIdx.x;            // 128
    const int layer = bx >> 6, o = bx & 63;
    const int wo = o >> 4, lo = o & 15;
    const int t = threadIdx.x;
    const float* src = (layer ? lc2 : lc1) + (size_t)o * 8192;
    __bf16* dst = layer ? o2 : o1;
    __shared__ float wbuf[64][130];
    // coalesced stage: flat i = c*128 + p
#pragma unroll
    for (int pass = 0; pass < 8; ++pass) {
        int i = pass * 1024 + t * 4;
        float4 v = *(const float4*)(src + i);
        int c = i >> 7, p = i & 127;
        wbuf[c][p + 0] = v.x; wbuf[c][p + 1] = v.y;
        wbuf[c][p + 2] = v.z; wbuf[c][p + 3] = v.w;
    }
    __syncthreads();
    // write frag chunks: slot = (p, chunk, q), 1024 slots
#pragma unroll
    for (int pass = 0; pass < 4; ++pass) {
        int slot = pass * 256 + t;
        int p = slot >> 3, chunk = (slot >> 2) & 1, q = slot & 3;
        bf16x8 v;
#pragma unroll
        for (int j = 0; j < 8; ++j)
            v[j] = (__bf16)wbuf[chunk * 32 + q * 8 + j][p];
        *(bf16x8*)(dst + ((size_t)((p * 2 + chunk) * 4 + wo) * 64 + q * 16 + lo) * 8) = v;
    }
}

// ===== prep: fc1 weights -> bf16 [n][kA], kA=p*64+c, coalesced via LDS ========
__global__ __launch_bounds__(256) void k_prep_fc1T(const float* __restrict__ fw,
                                                   __bf16* __restrict__ out) {
    const int n = blockIdx.x;             // 512
    const int t = threadIdx.x;
    const float* src = fw + (size_t)n * 8192;
    __bf16* dst = out + (size_t)n * 8192;
    __shared__ float wbuf[64][130];
#pragma unroll
    for (int pass = 0; pass < 8; ++pass) {
        int i = pass * 1024 + t * 4;      // i = c*128 + p
        float4 v = *(const float4*)(src + i);
        int c = i >> 7, p = i & 127;
        wbuf[c][p + 0] = v.x; wbuf[c][p + 1] = v.y;
        wbuf[c][p + 2] = v.z; wbuf[c][p + 3] = v.w;
    }
    __syncthreads();
#pragma unroll
    for (int pass = 0; pass < 16; ++pass) {
        int kA = (pass * 256 + t) * 2;    // even
        int c = kA & 63, p = kA >> 6;
        __bf16 tmp[2];
        tmp[0] = (__bf16)wbuf[c][p];
        tmp[1] = (__bf16)wbuf[c + 1][p];
        *(unsigned int*)(dst + kA) = *(unsigned int*)tmp;
    }
}

// ===== prep: cast fc2/fc3/out weights to bf16 (row-major [n][k] kept) ========
__global__ void k_cvt3(const float* __restrict__ w2, const float* __restrict__ w3,
                       const float* __restrict__ wo, __bf16* __restrict__ dst) {
    int i = blockIdx.x * 256 + threadIdx.x;   // 344064 total
    if (i >= 344064) return;
    float v;
    if (i < 262144) v = w2[i];
    else if (i < 327680) v = w3[i - 262144];
    else v = wo[i - 327680];
    dst[i] = (__bf16)v;
}

// ========== K1: bn0 + conv1(MFMA) + bn1relu + conv2(MFMA) + bn2relu ==========
__global__ __launch_bounds__(256) void k_conv_mfma(
    const float* __restrict__ inA, const float* __restrict__ inP, const float* __restrict__ inN,
    const float* __restrict__ bn0g, const float* __restrict__ bn0b,
    const float* __restrict__ bn0m, const float* __restrict__ bn0v,
    const __bf16* __restrict__ w1frag, const float* __restrict__ b1,
    const float* __restrict__ bn1g, const float* __restrict__ bn1b,
    const float* __restrict__ bn1m, const float* __restrict__ bn1v,
    const __bf16* __restrict__ w2frag, const float* __restrict__ b2,
    const float* __restrict__ bn2g, const float* __restrict__ bn2b,
    const float* __restrict__ bn2m, const float* __restrict__ bn2v,
    __bf16* __restrict__ act) {
    const int b = blockIdx.x, t = threadIdx.x;
    const int lane = t & 63, w = t >> 6;
    const int q = lane >> 4, li = lane & 15;
    const int n0 = w * 16;
    const float* src = (b < 512 ? inA : (b < 1024 ? inP : inN)) + (size_t)(b & 511) * 128;

    __shared__ __align__(16) float xpad[180];
    __shared__ __align__(16) __bf16 A1[128 * 40];
    __shared__ __align__(16) __bf16 Xp[18 * 12 * 72];
    __shared__ float s1[64], sh1[64], s2[64], sh2[64];

    bf16x8 w1f = *(const bf16x8*)(w1frag + (size_t)(w * 64 + lane) * 8);
    bf16x8 w2f[18];
#pragma unroll
    for (int tap = 0; tap < 9; ++tap)
#pragma unroll
        for (int ch = 0; ch < 2; ++ch)
            w2f[tap * 2 + ch] = *(const bf16x8*)(w2frag +
                ((size_t)((tap * 2 + ch) * 4 + w) * 64 + lane) * 8);

    {
        int* xz = (int*)Xp;
        for (int i = t; i < 7776; i += 256) xz[i] = 0;
        if (t < 180) xpad[t] = 0.f;
        if (t < 64) {
            float sa = bn1g[t] * rsqrtf(bn1v[t] + EPS);
            s1[t] = sa;
            sh1[t] = (b1[t] - bn1m[t]) * sa + bn1b[t];
            float sb = bn2g[t] * rsqrtf(bn2v[t] + EPS);
            s2[t] = sb;
            sh2[t] = (b2[t] - bn2m[t]) * sb + bn2b[t];
        }
    }
    __syncthreads();
    if (t < 128) {
        float s0 = bn0g[0] * rsqrtf(bn0v[0] + EPS);
        float v = (src[t] - bn0m[0]) * s0 + bn0b[0];
        xpad[((t >> 3) + 1) * 10 + (t & 7) + 1] = v;
    }
    __syncthreads();
    {
        int p = t >> 1, jh = (t & 1) * 16;
        int r = p >> 3, cl = p & 7;
#pragma unroll
        for (int jj = 0; jj < 16; ++jj) {
            int j = jh + jj;
            float v = 0.f;
            if (j < 9) v = xpad[(r + j / 3) * 10 + cl + (j % 3)];
            A1[p * 40 + j] = (__bf16)v;
        }
    }
    __syncthreads();
    {
        const float sco = s1[n0 + li], sho = sh1[n0 + li];
        const int o = n0 + li;
#pragma unroll
        for (int m = 0; m < 8; ++m) {
            bf16x8 a = *(const bf16x8*)&A1[(m * 16 + li) * 40 + q * 8];
            f32x4 z = {0.f, 0.f, 0.f, 0.f};
            f32x4 d = mfma16(a, w1f, z);
#pragma unroll
            for (int r = 0; r < 4; ++r) {
                int p = m * 16 + q * 4 + r;
                float v = fmaxf(d[r] * sco + sho, 0.f);
                Xp[(((p >> 3) + 1) * 12 + (p & 7) + 1) * 72 + o] = (__bf16)v;
            }
        }
    }
    __syncthreads();
    {
        const float sco = s2[n0 + li], sho = sh2[n0 + li];
        const int o = n0 + li;
        const int cl = li & 7;
#pragma unroll
        for (int mp = 0; mp < 4; ++mp) {
            const int m0t = mp * 2;
            const int r0 = m0t * 2 + (li >> 3);
            const int base0 = (r0 * 12 + cl) * 72 + q * 8;
            const int base1 = base0 + 1728;
            f32x4 acc0 = {0.f, 0.f, 0.f, 0.f};
            f32x4 acc1 = {0.f, 0.f, 0.f, 0.f};
#pragma unroll
            for (int tap = 0; tap < 9; ++tap) {
                const int tofs = ((tap / 3) * 12 + (tap % 3)) * 72;
#pragma unroll
                for (int ch = 0; ch < 2; ++ch) {
                    bf16x8 a0 = *(const bf16x8*)&Xp[base0 + tofs + ch * 32];
                    bf16x8 a1 = *(const bf16x8*)&Xp[base1 + tofs + ch * 32];
                    acc0 = mfma16(a0, w2f[tap * 2 + ch], acc0);
                    acc1 = mfma16(a1, w2f[tap * 2 + ch], acc1);
                }
            }
            __bf16* ob = act + (size_t)b * FD + o;
#pragma unroll
            for (int r = 0; r < 4; ++r) {
                int p0 = m0t * 16 + q * 4 + r;
                ob[p0 * 64] = (__bf16)fmaxf(acc0[r] * sco + sho, 0.f);
                ob[(p0 + 16) * 64] = (__bf16)fmaxf(acc1[r] * sco + sho, 0.f);
            }
        }
    }
}

// ========== K2: lc1 + bn3relu + lc2 + bn4relu (MFMA, in-place) ===============
__global__ __launch_bounds__(256) void k_lc_mfma(
    const __bf16* __restrict__ lc1frag, const __bf16* __restrict__ lc2frag,
    const float* __restrict__ bn3g, const float* __restrict__ bn3b,
    const float* __restrict__ bn3m, const float* __restrict__ bn3v,
    const float* __restrict__ bn4g, const float* __restrict__ bn4b,
    const float* __restrict__ bn4m, const float* __restrict__ bn4v,
    __bf16* __restrict__ act) {
    const int p = blockIdx.x;
    const int b0 = blockIdx.y * 64;
    const int t = threadIdx.x;
    const int lane = t & 63, w = t >> 6;
    const int q = lane >> 4, li = lane & 15;
    const int n0 = w * 16;

    __shared__ __align__(16) __bf16 xs[64 * 72];
    __shared__ __align__(16) __bf16 ys[64 * 72];
    __shared__ float s3[64], sh3[64], s4[64], sh4[64];

    if (t < 64) {
        float sa = bn3g[t] * rsqrtf(bn3v[t] + EPS);
        s3[t] = sa; sh3[t] = bn3b[t] - bn3m[t] * sa;
        float sb = bn4g[t] * rsqrtf(bn4v[t] + EPS);
        s4[t] = sb; sh4[t] = bn4b[t] - bn4m[t] * sb;
    }
    {
        int s = t >> 2, cg = t & 3;
        const __bf16* rp = act + (size_t)(b0 + s) * FD + p * 64 + cg * 16;
        *(bf16x8*)&xs[s * 72 + cg * 16] = *(const bf16x8*)rp;
        *(bf16x8*)&xs[s * 72 + cg * 16 + 8] = *(const bf16x8*)(rp + 8);
    }
    bf16x8 w1a = *(const bf16x8*)(lc1frag + ((size_t)((p * 2 + 0) * 4 + w) * 64 + lane) * 8);
    bf16x8 w1b = *(const bf16x8*)(lc1frag + ((size_t)((p * 2 + 1) * 4 + w) * 64 + lane) * 8);
    bf16x8 w2a = *(const bf16x8*)(lc2frag + ((size_t)((p * 2 + 0) * 4 + w) * 64 + lane) * 8);
    bf16x8 w2b = *(const bf16x8*)(lc2frag + ((size_t)((p * 2 + 1) * 4 + w) * 64 + lane) * 8);
    __syncthreads();
    {
        const float sco = s3[n0 + li], sho = sh3[n0 + li];
#pragma unroll
        for (int m = 0; m < 4; ++m) {
            bf16x8 a0 = *(const bf16x8*)&xs[(m * 16 + li) * 72 + q * 8];
            bf16x8 a1 = *(const bf16x8*)&xs[(m * 16 + li) * 72 + 32 + q * 8];
            f32x4 acc = {0.f, 0.f, 0.f, 0.f};
            acc = mfma16(a0, w1a, acc);
            acc = mfma16(a1, w1b, acc);
#pragma unroll
            for (int r = 0; r < 4; ++r) {
                int bl = m * 16 + q * 4 + r;
                ys[bl * 72 + n0 + li] = (__bf16)fmaxf(acc[r] * sco + sho, 0.f);
            }
        }
    }
    __syncthreads();
    {
        const float sco = s4[n0 + li], sho = sh4[n0 + li];
#pragma unroll
        for (int m = 0; m < 4; ++m) {
            bf16x8 a0 = *(const bf16x8*)&ys[(m * 16 + li) * 72 + q * 8];
            bf16x8 a1 = *(const bf16x8*)&ys[(m * 16 + li) * 72 + 32 + q * 8];
            f32x4 acc = {0.f, 0.f, 0.f, 0.f};
            acc = mfma16(a0, w2a, acc);
            acc = mfma16(a1, w2b, acc);
#pragma unroll
            for (int r = 0; r < 4; ++r) {
                int bl = m * 16 + q * 4 + r;
                act[(size_t)(b0 + bl) * FD + p * 64 + n0 + li] =
                    (__bf16)fmaxf(acc[r] * sco + sho, 0.f);
            }
        }
    }
}

// ========== K3: fc1 MFMA 64x128 tile, split-K 8, fp32 partials ===============
__global__ __launch_bounds__(256) void k_fc1_mfma(
    const __bf16* __restrict__ A, const __bf16* __restrict__ Wb,
    float* __restrict__ part) {
    const int t = threadIdx.x;
    const int lane = t & 63, w = t >> 6;
    const int q = lane >> 4, li = lane & 15;
    const int m0 = blockIdx.x * 64, n0 = blockIdx.y * 128;
    const int k0 = blockIdx.z * 1024;
    const int wm = (w & 1) * 32, wn = (w >> 1) * 64;

    __shared__ __align__(16) __bf16 As[64 * 40];
    __shared__ __align__(16) __bf16 Bs[128 * 40];

    f32x4 acc[2][4];
#pragma unroll
    for (int i = 0; i < 2; ++i)
#pragma unroll
        for (int j = 0; j < 4; ++j) acc[i][j] = (f32x4){0.f, 0.f, 0.f, 0.f};

    const int rowA = (t & 127) >> 1, rowB = t >> 1, half = t & 1;
    const __bf16* Ag = A + (size_t)(m0 + rowA) * 8192 + k0 + half * 16;
    const __bf16* Bg = Wb + (size_t)(n0 + rowB) * 8192 + k0 + half * 16;

    for (int step = 0; step < 32; ++step) {
        bf16x8 b0 = *(const bf16x8*)Bg;
        bf16x8 b1 = *(const bf16x8*)(Bg + 8);
        if (t < 128) {
            bf16x8 a0 = *(const bf16x8*)Ag;
            bf16x8 a1 = *(const bf16x8*)(Ag + 8);
            *(bf16x8*)&As[rowA * 40 + half * 16] = a0;
            *(bf16x8*)&As[rowA * 40 + half * 16 + 8] = a1;
        }
        *(bf16x8*)&Bs[rowB * 40 + half * 16] = b0;
        *(bf16x8*)&Bs[rowB * 40 + half * 16 + 8] = b1;
        __syncthreads();
        bf16x8 af[2], bfr[4];
#pragma unroll
        for (int i = 0; i < 2; ++i)
            af[i] = *(const bf16x8*)&As[(wm + i * 16 + li) * 40 + q * 8];
#pragma unroll
        for (int j = 0; j < 4; ++j)
            bfr[j] = *(const bf16x8*)&Bs[(wn + j * 16 + li) * 40 + q * 8];
#pragma unroll
        for (int i = 0; i < 2; ++i)
#pragma unroll
            for (int j = 0; j < 4; ++j)
                acc[i][j] = mfma16(af[i], bfr[j], acc[i][j]);
        __syncthreads();
        Ag += 32;
        Bg += 32;
    }
    float* pp = part + (size_t)blockIdx.z * 786432;
#pragma unroll
    for (int i = 0; i < 2; ++i) {
#pragma unroll
        for (int r = 0; r < 4; ++r) {
            int m = m0 + wm + i * 16 + q * 4 + r;
#pragma unroll
            for (int j = 0; j < 4; ++j) {
                int n = n0 + wn + j * 16 + li;
                pp[(size_t)m * 512 + n] = acc[i][j][r];
            }
        }
    }
}

// reduce 8 partials + bias + bn + relu -> bf16 act3
__global__ void k_fc1_reduce(const float* __restrict__ part, const float* __restrict__ bias,
                             const float* __restrict__ g, const float* __restrict__ bb,
                             const float* __restrict__ mm, const float* __restrict__ vv,
                             __bf16* __restrict__ out) {
    int gi = blockIdx.x * 256 + threadIdx.x;   // 196608 float4s
    size_t off = (size_t)gi * 4;
    float4 s = make_float4(0.f, 0.f, 0.f, 0.f);
#pragma unroll
    for (int z = 0; z < 8; ++z) {
        float4 v = *(const float4*)(part + (size_t)z * 786432 + off);
        s.x += v.x; s.y += v.y; s.z += v.z; s.w += v.w;
    }
    int n = (gi & 127) * 4;
    float r[4] = {s.x, s.y, s.z, s.w};
    __bf16 o4[4];
#pragma unroll
    for (int j = 0; j < 4; ++j) {
        float sc = g[n + j] * rsqrtf(vv[n + j] + EPS);
        float x = (r[j] + bias[n + j] - mm[n + j]) * sc + bb[n + j];
        o4[j] = (__bf16)fmaxf(x, 0.f);
    }
    *(uint2*)(out + off) = *(uint2*)o4;
}

// ========= generic bf16 MFMA GEMM 64x64 tile, fused epilogue =================
// out = A(M,K) @ W(N,K)^T ; FINAL -> fp32 out, else bf16
template <int FINAL>
__global__ __launch_bounds__(256) void k_fc_mfma(
    const __bf16* __restrict__ A, const __bf16* __restrict__ W,
    const float* __restrict__ bias,
    const float* __restrict__ bng, const float* __restrict__ bnb,
    const float* __restrict__ bnm, const float* __restrict__ bnv,
    void* __restrict__ out, int N, int K, int relu) {
    const int t = threadIdx.x;
    const int lane = t & 63, w = t >> 6;
    const int q = lane >> 4, li = lane & 15;
    const int m0 = blockIdx.x * 64, n0 = blockIdx.y * 64;
    const int wm = (w & 1) * 32, wn = (w >> 1) * 32;

    __shared__ __align__(16) __bf16 As[64 * 40];
    __shared__ __align__(16) __bf16 Bs[64 * 40];

    f32x4 acc[2][2];
#pragma unroll
    for (int i = 0; i < 2; ++i)
#pragma unroll
        for (int j = 0; j < 2; ++j) acc[i][j] = (f32x4){0.f, 0.f, 0.f, 0.f};

    const int row = (t & 127) >> 1, half = t & 1;
    const __bf16* g = (t < 128 ? A + (size_t)(m0 + row) * K
                               : W + (size_t)(n0 + row) * K) + half * 16;
    __bf16* ld = (t < 128 ? As : Bs) + row * 40 + half * 16;

    for (int k0 = 0; k0 < K; k0 += 32) {
        bf16x8 v0 = *(const bf16x8*)g;
        bf16x8 v1 = *(const bf16x8*)(g + 8);
        *(bf16x8*)ld = v0;
        *(bf16x8*)(ld + 8) = v1;
        __syncthreads();
        bf16x8 af[2], bfr[2];
#pragma unroll
        for (int i = 0; i < 2; ++i)
            af[i] = *(const bf16x8*)&As[(wm + i * 16 + li) * 40 + q * 8];
#pragma unroll
        for (int j = 0; j < 2; ++j)
            bfr[j] = *(const bf16x8*)&Bs[(wn + j * 16 + li) * 40 + q * 8];
#pragma unroll
        for (int i = 0; i < 2; ++i)
#pragma unroll
            for (int j = 0; j < 2; ++j)
                acc[i][j] = mfma16(af[i], bfr[j], acc[i][j]);
        __syncthreads();
        g += 32;
    }
    float bi[2], sc[2], hh[2];
#pragma unroll
    for (int j = 0; j < 2; ++j) {
        int n = n0 + wn + j * 16 + li;
        bi[j] = bias[n];
        if (bng) {
            sc[j] = bng[n] * rsqrtf(bnv[n] + EPS);
            hh[j] = bnb[n] - bnm[n] * sc[j];
        }
    }
#pragma unroll
    for (int i = 0; i < 2; ++i) {
#pragma unroll
        for (int r = 0; r < 4; ++r) {
            int m = m0 + wm + i * 16 + q * 4 + r;
#pragma unroll
            for (int j = 0; j < 2; ++j) {
                int n = n0 + wn + j * 16 + li;
                float x = acc[i][j][r] + bi[j];
                if (bng) x = x * sc[j] + hh[j];
                if (relu) x = fmaxf(x, 0.f);
                if (FINAL) ((float*)out)[(size_t)m * N + n] = x;
                else ((__bf16*)out)[(size_t)m * N + n] = (__bf16)x;
            }
        }
    }
}

extern "C" void kernel_launch(void* const* d_in, const int* in_sizes, int n_in,
                              void* d_out, int out_size, void* d_ws, size_t ws_size,
                              hipStream_t stream) {
    const float* inA    = (const float*)d_in[0];
    const float* inP    = (const float*)d_in[1];
    const float* inN    = (const float*)d_in[2];
    const float* bn0g   = (const float*)d_in[3];
    const float* bn0b   = (const float*)d_in[4];
    const float* bn0m   = (const float*)d_in[5];
    const float* bn0v   = (const float*)d_in[6];
    const float* conv1w = (const float*)d_in[7];
    const float* conv1b = (const float*)d_in[8];
    const float* bn1g   = (const float*)d_in[9];
    const float* bn1b   = (const float*)d_in[10];
    const float* bn1m   = (const float*)d_in[11];
    const float* bn1v   = (const float*)d_in[12];
    const float* conv2w = (const float*)d_in[13];
    const float* conv2b = (const float*)d_in[14];
    const float* bn2g   = (const float*)d_in[15];
    const float* bn2b   = (const float*)d_in[16];
    const float* bn2m   = (const float*)d_in[17];
    const float* bn2v   = (const float*)d_in[18];
    const float* lc1w   = (const float*)d_in[19];
    const float* bn3g   = (const float*)d_in[20];
    const float* bn3b   = (const float*)d_in[21];
    const float* bn3m   = (const float*)d_in[22];
    const float* bn3v   = (const float*)d_in[23];
    const float* lc2w   = (const float*)d_in[24];
    const float* bn4g   = (const float*)d_in[25];
    const float* bn4b   = (const float*)d_in[26];
    const float* bn4m   = (const float*)d_in[27];
    const float* bn4v   = (const float*)d_in[28];
    const float* fc1w   = (const float*)d_in[29];
    const float* fc1b   = (const float*)d_in[30];
    const float* bnf1g  = (const float*)d_in[31];
    const float* bnf1b  = (const float*)d_in[32];
    const float* bnf1m  = (const float*)d_in[33];
    const float* bnf1v  = (const float*)d_in[34];
    const float* fc2w   = (const float*)d_in[35];
    const float* fc2b   = (const float*)d_in[36];
    const float* bnf2g  = (const float*)d_in[37];
    const float* bnf2b  = (const float*)d_in[38];
    const float* bnf2m  = (const float*)d_in[39];
    const float* bnf2v  = (const float*)d_in[40];
    const float* fc3w   = (const float*)d_in[41];
    const float* fc3b   = (const float*)d_in[42];
    const float* bnf3g  = (const float*)d_in[43];
    const float* bnf3b  = (const float*)d_in[44];
    const float* bnf3m  = (const float*)d_in[45];
    const float* bnf3v  = (const float*)d_in[46];
    const float* outw   = (const float*)d_in[47];
    const float* outb   = (const float*)d_in[48];

    char* wsb = (char*)d_ws;
    __bf16* w1frag  = (__bf16*)wsb;                        // 2048 el
    __bf16* w2frag  = w1frag + 2048;                       // 36864 el
    __bf16* lc1frag = w2frag + 36864;                      // 524288 el
    __bf16* lc2frag = lc1frag + 524288;                    // 524288 el
    __bf16* fc1Wb   = lc2frag + 524288;                    // 4194304 el
    __bf16* wf23    = fc1Wb + 4194304;                     // 344064 el (fc2|fc3|out)
    __bf16* act     = wf23 + 344064;                       // 12582912 el
    __bf16* act3    = act + 12582912;                      // 786432 el
    __bf16* act4    = act3 + 786432;                       // 786432 el
    __bf16* act5    = act4 + 786432;                       // 196608 el
    // align part to 16B
    float*  part    = (float*)(((uintptr_t)(act5 + 196608) + 15) & ~(uintptr_t)15);
    __bf16* wf2 = wf23;
    __bf16* wf3 = wf23 + 262144;
    __bf16* wfo = wf23 + 327680;

    // ---- weight prep ----
    k_prep_w1frag<<<1, 256, 0, stream>>>(conv1w, w1frag);
    k_prep_w2frag<<<18, 256, 0, stream>>>(conv2w, w2frag);
    k_prep_lcT<<<128, 256, 0, stream>>>(lc1w, lc2w, lc1frag, lc2frag);
    k_prep_fc1T<<<512, 256, 0, stream>>>(fc1w, fc1Wb);
    k_cvt3<<<1344, 256, 0, stream>>>(fc2w, fc3w, outw, wf23);

    // ---- conv stage (MFMA) ----
    k_conv_mfma<<<1536, 256, 0, stream>>>(inA, inP, inN,
        bn0g, bn0b, bn0m, bn0v, w1frag, conv1b, bn1g, bn1b, bn1m, bn1v,
        w2frag, conv2b, bn2g, bn2b, bn2m, bn2v, act);

    // ---- locally connected (MFMA, in place) ----
    k_lc_mfma<<<dim3(128, 24), 256, 0, stream>>>(lc1frag, lc2frag,
        bn3g, bn3b, bn3m, bn3v, bn4g, bn4b, bn4m, bn4v, act);

    // ---- fc1 (MFMA split-K 8) + reduce ----
    k_fc1_mfma<<<dim3(24, 4, 8), 256, 0, stream>>>(act, fc1Wb, part);
    k_fc1_reduce<<<768, 256, 0, stream>>>(part, fc1b, bnf1g, bnf1b, bnf1m, bnf1v, act3);

    // ---- fc2 / fc3 / out (MFMA) ----
    k_fc_mfma<0><<<dim3(24, 8), 256, 0, stream>>>(act3, wf2, fc2b,
        bnf2g, bnf2b, bnf2m, bnf2v, act4, 512, 512, 1);
    k_fc_mfma<0><<<dim3(24, 2), 256, 0, stream>>>(act4, wf3, fc3b,
        bnf3g, bnf3b, bnf3m, bnf3v, act5, 128, 512, 1);
    k_fc_mfma<1><<<dim3(24, 2), 256, 0, stream>>>(act5, wfo, outb,
        nullptr, nullptr, nullptr, nullptr, d_out, 128, 128, 0);
}

// Round 4
// 250.808 us; speedup vs baseline: 2.7693x; 1.0456x over previous
//
#include <hip/hip_runtime.h>
#include <math.h>

#define EPS 1e-5f
#define FD 8192

typedef __attribute__((ext_vector_type(8))) __bf16 bf16x8;
typedef __attribute__((ext_vector_type(4))) float f32x4;

static __device__ __forceinline__ f32x4 mfma16(bf16x8 a, bf16x8 b, f32x4 c) {
    return __builtin_amdgcn_mfma_f32_16x16x32_bf16(a, b, c, 0, 0, 0);
}

// ================= merged weight prep (one launch) ===========================
// blocks: [0] w1frag | [1,19) w2frag | [19,147) lcT | [147,659) fc1T | [659,2003) cvt3
__global__ __launch_bounds__(256) void k_prep_all(
    const float* __restrict__ w1, const float* __restrict__ w2,
    const float* __restrict__ lc1, const float* __restrict__ lc2,
    const float* __restrict__ fc1w, const float* __restrict__ fc2w,
    const float* __restrict__ fc3w, const float* __restrict__ outw,
    __bf16* __restrict__ w1frag, __bf16* __restrict__ w2frag,
    __bf16* __restrict__ lc1frag, __bf16* __restrict__ lc2frag,
    __bf16* __restrict__ fc1Wb, __bf16* __restrict__ wf23) {
    const int bb = blockIdx.x;
    const int t = threadIdx.x;
    __shared__ float wbuf[64][130];

    if (bb == 0) {
        // conv1 weights -> B-fragment order (K=32 padded from 9)
        const int lane = t & 63, w = t >> 6;
        const int q = lane >> 4, li = lane & 15;
        const int o = w * 16 + li;
        bf16x8 v;
#pragma unroll
        for (int j = 0; j < 8; ++j) {
            int k = q * 8 + j;
            v[j] = (k < 9) ? (__bf16)w1[o * 9 + k] : (__bf16)0.0f;
        }
        *(bf16x8*)(w1frag + t * 8) = v;
    } else if (bb < 19) {
        // conv2 weights -> B-fragment order per (tap,chunk,w)
        const int id = (bb - 1) * 256 + t;
        const int lane = id & 63;
        const int w = (id >> 6) & 3;
        const int chunk = (id >> 8) & 1;
        const int tap = id >> 9;
        const int q = lane >> 4, li = lane & 15;
        const int o = w * 16 + li;
        const int c0 = chunk * 32 + q * 8;
        bf16x8 v;
#pragma unroll
        for (int j = 0; j < 8; ++j)
            v[j] = (__bf16)w2[(o * 64 + c0 + j) * 9 + tap];
        *(bf16x8*)(w2frag + (size_t)id * 8) = v;
    } else if (bb < 147) {
        // lc weights -> frag order, coalesced via LDS; block per (layer,o)
        const int bx = bb - 19;
        const int layer = bx >> 6, o = bx & 63;
        const int wo = o >> 4, lo = o & 15;
        const float* src = (layer ? lc2 : lc1) + (size_t)o * 8192;
        __bf16* dst = layer ? lc2frag : lc1frag;
#pragma unroll
        for (int pass = 0; pass < 8; ++pass) {
            int i = pass * 1024 + t * 4;
            float4 v = *(const float4*)(src + i);
            int c = i >> 7, p = i & 127;
            wbuf[c][p + 0] = v.x; wbuf[c][p + 1] = v.y;
            wbuf[c][p + 2] = v.z; wbuf[c][p + 3] = v.w;
        }
        __syncthreads();
#pragma unroll
        for (int pass = 0; pass < 4; ++pass) {
            int slot = pass * 256 + t;
            int p = slot >> 3, chunk = (slot >> 2) & 1, q = slot & 3;
            bf16x8 v;
#pragma unroll
            for (int j = 0; j < 8; ++j)
                v[j] = (__bf16)wbuf[chunk * 32 + q * 8 + j][p];
            *(bf16x8*)(dst + ((size_t)((p * 2 + chunk) * 4 + wo) * 64 + q * 16 + lo) * 8) = v;
        }
    } else if (bb < 659) {
        // fc1 weights -> bf16 [n][kA], kA = p*64+c
        const int n = bb - 147;
        const float* src = fc1w + (size_t)n * 8192;
        __bf16* dst = fc1Wb + (size_t)n * 8192;
#pragma unroll
        for (int pass = 0; pass < 8; ++pass) {
            int i = pass * 1024 + t * 4;
            float4 v = *(const float4*)(src + i);
            int c = i >> 7, p = i & 127;
            wbuf[c][p + 0] = v.x; wbuf[c][p + 1] = v.y;
            wbuf[c][p + 2] = v.z; wbuf[c][p + 3] = v.w;
        }
        __syncthreads();
#pragma unroll
        for (int pass = 0; pass < 16; ++pass) {
            int kA = (pass * 256 + t) * 2;
            int c = kA & 63, p = kA >> 6;
            __bf16 tmp[2];
            tmp[0] = (__bf16)wbuf[c][p];
            tmp[1] = (__bf16)wbuf[c + 1][p];
            *(unsigned int*)(dst + kA) = *(unsigned int*)tmp;
        }
    } else {
        // cast fc2/fc3/out weights to bf16
        int i = (bb - 659) * 256 + t;
        float v;
        if (i < 262144) v = fc2w[i];
        else if (i < 327680) v = fc3w[i - 262144];
        else v = outw[i - 327680];
        wf23[i] = (__bf16)v;
    }
}

// ========== K1: bn0 + conv1(MFMA) + bn1relu + conv2(MFMA) + bn2relu ==========
// one block per sample; writes act (bf16) layout [b][p*64 + c], coalesced
__global__ __launch_bounds__(256) void k_conv_mfma(
    const float* __restrict__ inA, const float* __restrict__ inP, const float* __restrict__ inN,
    const float* __restrict__ bn0g, const float* __restrict__ bn0b,
    const float* __restrict__ bn0m, const float* __restrict__ bn0v,
    const __bf16* __restrict__ w1frag, const float* __restrict__ b1,
    const float* __restrict__ bn1g, const float* __restrict__ bn1b,
    const float* __restrict__ bn1m, const float* __restrict__ bn1v,
    const __bf16* __restrict__ w2frag, const float* __restrict__ b2,
    const float* __restrict__ bn2g, const float* __restrict__ bn2b,
    const float* __restrict__ bn2m, const float* __restrict__ bn2v,
    __bf16* __restrict__ act) {
    const int b = blockIdx.x, t = threadIdx.x;
    const int lane = t & 63, w = t >> 6;
    const int q = lane >> 4, li = lane & 15;
    const int n0 = w * 16;
    const float* src = (b < 512 ? inA : (b < 1024 ? inP : inN)) + (size_t)(b & 511) * 128;

    __shared__ __align__(16) float xpad[180];
    __shared__ __align__(16) __bf16 A1[128 * 40];
    __shared__ __align__(16) __bf16 Xp[18 * 12 * 72];   // also reused as repack buf
    __shared__ float s1[64], sh1[64], s2[64], sh2[64];

    bf16x8 w1f = *(const bf16x8*)(w1frag + (size_t)(w * 64 + lane) * 8);
    bf16x8 w2f[18];
#pragma unroll
    for (int tap = 0; tap < 9; ++tap)
#pragma unroll
        for (int ch = 0; ch < 2; ++ch)
            w2f[tap * 2 + ch] = *(const bf16x8*)(w2frag +
                ((size_t)((tap * 2 + ch) * 4 + w) * 64 + lane) * 8);

    {
        int* xz = (int*)Xp;
        for (int i = t; i < 7776; i += 256) xz[i] = 0;
        if (t < 180) xpad[t] = 0.f;
        if (t < 64) {
            float sa = bn1g[t] * rsqrtf(bn1v[t] + EPS);
            s1[t] = sa;
            sh1[t] = (b1[t] - bn1m[t]) * sa + bn1b[t];
            float sb = bn2g[t] * rsqrtf(bn2v[t] + EPS);
            s2[t] = sb;
            sh2[t] = (b2[t] - bn2m[t]) * sb + bn2b[t];
        }
    }
    __syncthreads();
    if (t < 128) {
        float s0 = bn0g[0] * rsqrtf(bn0v[0] + EPS);
        float v = (src[t] - bn0m[0]) * s0 + bn0b[0];
        xpad[((t >> 3) + 1) * 10 + (t & 7) + 1] = v;
    }
    __syncthreads();
    {   // im2col A1[p][k], vectorized b128 writes
        int p = t >> 1, half = t & 1;
        int r = p >> 3, cl = p & 7;
        bf16x8 v0, v1;
#pragma unroll
        for (int jj = 0; jj < 8; ++jj) {
            int j = half * 16 + jj;
            v0[jj] = (j < 9) ? (__bf16)xpad[(r + j / 3) * 10 + cl + (j % 3)] : (__bf16)0.f;
            int j2 = half * 16 + 8 + jj;
            v1[jj] = (j2 < 9) ? (__bf16)xpad[(r + j2 / 3) * 10 + cl + (j2 % 3)] : (__bf16)0.f;
        }
        *(bf16x8*)&A1[p * 40 + half * 16] = v0;
        *(bf16x8*)&A1[p * 40 + half * 16 + 8] = v1;
    }
    __syncthreads();
    {   // conv1 MFMA, bn1+relu -> Xp interior (c-inner)
        const float sco = s1[n0 + li], sho = sh1[n0 + li];
        const int o = n0 + li;
#pragma unroll
        for (int m = 0; m < 8; ++m) {
            bf16x8 a = *(const bf16x8*)&A1[(m * 16 + li) * 40 + q * 8];
            f32x4 z = {0.f, 0.f, 0.f, 0.f};
            f32x4 d = mfma16(a, w1f, z);
#pragma unroll
            for (int r = 0; r < 4; ++r) {
                int p = m * 16 + q * 4 + r;
                float v = fmaxf(d[r] * sco + sho, 0.f);
                Xp[(((p >> 3) + 1) * 12 + (p & 7) + 1) * 72 + o] = (__bf16)v;
            }
        }
    }
    __syncthreads();
    // conv2 implicit GEMM: accumulate ALL tiles in registers first
    f32x4 accA[4], accB[4];
#pragma unroll
    for (int i = 0; i < 4; ++i) {
        accA[i] = (f32x4){0.f, 0.f, 0.f, 0.f};
        accB[i] = (f32x4){0.f, 0.f, 0.f, 0.f};
    }
    {
        const int cl = li & 7;
#pragma unroll
        for (int mp = 0; mp < 4; ++mp) {
            const int r0 = mp * 4 + (li >> 3);
            const int base0 = (r0 * 12 + cl) * 72 + q * 8;
            const int base1 = base0 + 1728;               // +2 rows
#pragma unroll
            for (int tap = 0; tap < 9; ++tap) {
                const int tofs = ((tap / 3) * 12 + (tap % 3)) * 72;
#pragma unroll
                for (int ch = 0; ch < 2; ++ch) {
                    bf16x8 a0 = *(const bf16x8*)&Xp[base0 + tofs + ch * 32];
                    bf16x8 a1 = *(const bf16x8*)&Xp[base1 + tofs + ch * 32];
                    accA[mp] = mfma16(a0, w2f[tap * 2 + ch], accA[mp]);
                    accB[mp] = mfma16(a1, w2f[tap * 2 + ch], accB[mp]);
                }
            }
        }
    }
    __syncthreads();   // all Xp reads done; reuse as repack buffer (stride 72)
    {
        const float sco = s2[n0 + li], sho = sh2[n0 + li];
        const int o = n0 + li;
#pragma unroll
        for (int mp = 0; mp < 4; ++mp) {
#pragma unroll
            for (int r = 0; r < 4; ++r) {
                int p0 = mp * 32 + q * 4 + r;
                Xp[p0 * 72 + o] = (__bf16)fmaxf(accA[mp][r] * sco + sho, 0.f);
                Xp[(p0 + 16) * 72 + o] = (__bf16)fmaxf(accB[mp][r] * sco + sho, 0.f);
            }
        }
    }
    __syncthreads();
    {   // cooperative coalesced store: 64B per thread
        int p = t >> 1, half = t & 1;
        const __bf16* rp = Xp + p * 72 + half * 32;
        __bf16* ob = act + (size_t)b * FD + p * 64 + half * 32;
        bf16x8 v0 = *(const bf16x8*)rp;
        bf16x8 v1 = *(const bf16x8*)(rp + 8);
        bf16x8 v2 = *(const bf16x8*)(rp + 16);
        bf16x8 v3 = *(const bf16x8*)(rp + 24);
        *(bf16x8*)ob = v0;
        *(bf16x8*)(ob + 8) = v1;
        *(bf16x8*)(ob + 16) = v2;
        *(bf16x8*)(ob + 24) = v3;
    }
}

// ========== K2: lc1 + bn3relu + lc2 + bn4relu (MFMA, in-place) ===============
__global__ __launch_bounds__(256) void k_lc_mfma(
    const __bf16* __restrict__ lc1frag, const __bf16* __restrict__ lc2frag,
    const float* __restrict__ bn3g, const float* __restrict__ bn3b,
    const float* __restrict__ bn3m, const float* __restrict__ bn3v,
    const float* __restrict__ bn4g, const float* __restrict__ bn4b,
    const float* __restrict__ bn4m, const float* __restrict__ bn4v,
    __bf16* __restrict__ act) {
    const int p = blockIdx.x;
    const int b0 = blockIdx.y * 64;
    const int t = threadIdx.x;
    const int lane = t & 63, w = t >> 6;
    const int q = lane >> 4, li = lane & 15;
    const int n0 = w * 16;

    __shared__ __align__(16) __bf16 xs[64 * 72];
    __shared__ __align__(16) __bf16 ys[64 * 72];
    __shared__ float s3[64], sh3[64], s4[64], sh4[64];

    if (t < 64) {
        float sa = bn3g[t] * rsqrtf(bn3v[t] + EPS);
        s3[t] = sa; sh3[t] = bn3b[t] - bn3m[t] * sa;
        float sb = bn4g[t] * rsqrtf(bn4v[t] + EPS);
        s4[t] = sb; sh4[t] = bn4b[t] - bn4m[t] * sb;
    }
    {
        int s = t >> 2, cg = t & 3;
        const __bf16* rp = act + (size_t)(b0 + s) * FD + p * 64 + cg * 16;
        *(bf16x8*)&xs[s * 72 + cg * 16] = *(const bf16x8*)rp;
        *(bf16x8*)&xs[s * 72 + cg * 16 + 8] = *(const bf16x8*)(rp + 8);
    }
    bf16x8 w1a = *(const bf16x8*)(lc1frag + ((size_t)((p * 2 + 0) * 4 + w) * 64 + lane) * 8);
    bf16x8 w1b = *(const bf16x8*)(lc1frag + ((size_t)((p * 2 + 1) * 4 + w) * 64 + lane) * 8);
    bf16x8 w2a = *(const bf16x8*)(lc2frag + ((size_t)((p * 2 + 0) * 4 + w) * 64 + lane) * 8);
    bf16x8 w2b = *(const bf16x8*)(lc2frag + ((size_t)((p * 2 + 1) * 4 + w) * 64 + lane) * 8);
    __syncthreads();
    {   // layer 1 -> ys
        const float sco = s3[n0 + li], sho = sh3[n0 + li];
#pragma unroll
        for (int m = 0; m < 4; ++m) {
            bf16x8 a0 = *(const bf16x8*)&xs[(m * 16 + li) * 72 + q * 8];
            bf16x8 a1 = *(const bf16x8*)&xs[(m * 16 + li) * 72 + 32 + q * 8];
            f32x4 acc = {0.f, 0.f, 0.f, 0.f};
            acc = mfma16(a0, w1a, acc);
            acc = mfma16(a1, w1b, acc);
#pragma unroll
            for (int r = 0; r < 4; ++r) {
                int bl = m * 16 + q * 4 + r;
                ys[bl * 72 + n0 + li] = (__bf16)fmaxf(acc[r] * sco + sho, 0.f);
            }
        }
    }
    __syncthreads();
    {   // layer 2 -> xs (repack), then coalesced store
        const float sco = s4[n0 + li], sho = sh4[n0 + li];
#pragma unroll
        for (int m = 0; m < 4; ++m) {
            bf16x8 a0 = *(const bf16x8*)&ys[(m * 16 + li) * 72 + q * 8];
            bf16x8 a1 = *(const bf16x8*)&ys[(m * 16 + li) * 72 + 32 + q * 8];
            f32x4 acc = {0.f, 0.f, 0.f, 0.f};
            acc = mfma16(a0, w2a, acc);
            acc = mfma16(a1, w2b, acc);
#pragma unroll
            for (int r = 0; r < 4; ++r) {
                int bl = m * 16 + q * 4 + r;
                xs[bl * 72 + n0 + li] = (__bf16)fmaxf(acc[r] * sco + sho, 0.f);
            }
        }
    }
    __syncthreads();
    {
        int s = t >> 2, cg = t & 3;
        const __bf16* rp = xs + s * 72 + cg * 16;
        __bf16* ob = act + (size_t)(b0 + s) * FD + p * 64 + cg * 16;
        bf16x8 v0 = *(const bf16x8*)rp;
        bf16x8 v1 = *(const bf16x8*)(rp + 8);
        *(bf16x8*)ob = v0;
        *(bf16x8*)(ob + 8) = v1;
    }
}

// ========== K3: fc1 MFMA 64x128 tile, split-K 8, reg-prefetch ================
__global__ __launch_bounds__(256) void k_fc1_mfma(
    const __bf16* __restrict__ A, const __bf16* __restrict__ Wb,
    float* __restrict__ part) {
    const int t = threadIdx.x;
    const int lane = t & 63, w = t >> 6;
    const int q = lane >> 4, li = lane & 15;
    const int m0 = blockIdx.x * 64, n0 = blockIdx.y * 128;
    const int k0 = blockIdx.z * 1024;
    const int wm = (w & 1) * 32, wn = (w >> 1) * 64;

    __shared__ __align__(16) __bf16 As[64 * 40];
    __shared__ __align__(16) __bf16 Bs[128 * 40];

    f32x4 acc[2][4];
#pragma unroll
    for (int i = 0; i < 2; ++i)
#pragma unroll
        for (int j = 0; j < 4; ++j) acc[i][j] = (f32x4){0.f, 0.f, 0.f, 0.f};

    const int rowA = (t & 127) >> 1, rowB = t >> 1, half = t & 1;
    const __bf16* Ag = A + (size_t)(m0 + rowA) * 8192 + k0 + half * 16;
    const __bf16* Bg = Wb + (size_t)(n0 + rowB) * 8192 + k0 + half * 16;

    bf16x8 pa0, pa1, pb0, pb1;
    pb0 = *(const bf16x8*)Bg;
    pb1 = *(const bf16x8*)(Bg + 8);
    if (t < 128) {
        pa0 = *(const bf16x8*)Ag;
        pa1 = *(const bf16x8*)(Ag + 8);
    }

    for (int step = 0; step < 32; ++step) {
        if (t < 128) {
            *(bf16x8*)&As[rowA * 40 + half * 16] = pa0;
            *(bf16x8*)&As[rowA * 40 + half * 16 + 8] = pa1;
        }
        *(bf16x8*)&Bs[rowB * 40 + half * 16] = pb0;
        *(bf16x8*)&Bs[rowB * 40 + half * 16 + 8] = pb1;
        __syncthreads();
        Ag += 32; Bg += 32;
        if (step < 31) {   // prefetch next chunk; overlaps MFMAs below
            pb0 = *(const bf16x8*)Bg;
            pb1 = *(const bf16x8*)(Bg + 8);
            if (t < 128) {
                pa0 = *(const bf16x8*)Ag;
                pa1 = *(const bf16x8*)(Ag + 8);
            }
        }
        bf16x8 af[2], bfr[4];
#pragma unroll
        for (int i = 0; i < 2; ++i)
            af[i] = *(const bf16x8*)&As[(wm + i * 16 + li) * 40 + q * 8];
#pragma unroll
        for (int j = 0; j < 4; ++j)
            bfr[j] = *(const bf16x8*)&Bs[(wn + j * 16 + li) * 40 + q * 8];
#pragma unroll
        for (int i = 0; i < 2; ++i)
#pragma unroll
            for (int j = 0; j < 4; ++j)
                acc[i][j] = mfma16(af[i], bfr[j], acc[i][j]);
        __syncthreads();
    }
    float* pp = part + (size_t)blockIdx.z * 786432;
#pragma unroll
    for (int i = 0; i < 2; ++i) {
#pragma unroll
        for (int r = 0; r < 4; ++r) {
            int m = m0 + wm + i * 16 + q * 4 + r;
#pragma unroll
            for (int j = 0; j < 4; ++j) {
                int n = n0 + wn + j * 16 + li;
                pp[(size_t)m * 512 + n] = acc[i][j][r];
            }
        }
    }
}

// reduce 8 partials + bias + bn + relu -> bf16 act3
__global__ void k_fc1_reduce(const float* __restrict__ part, const float* __restrict__ bias,
                             const float* __restrict__ g, const float* __restrict__ bb,
                             const float* __restrict__ mm, const float* __restrict__ vv,
                             __bf16* __restrict__ out) {
    int gi = blockIdx.x * 256 + threadIdx.x;
    size_t off = (size_t)gi * 4;
    float4 s = make_float4(0.f, 0.f, 0.f, 0.f);
#pragma unroll
    for (int z = 0; z < 8; ++z) {
        float4 v = *(const float4*)(part + (size_t)z * 786432 + off);
        s.x += v.x; s.y += v.y; s.z += v.z; s.w += v.w;
    }
    int n = (gi & 127) * 4;
    float r[4] = {s.x, s.y, s.z, s.w};
    __bf16 o4[4];
#pragma unroll
    for (int j = 0; j < 4; ++j) {
        float sc = g[n + j] * rsqrtf(vv[n + j] + EPS);
        float x = (r[j] + bias[n + j] - mm[n + j]) * sc + bb[n + j];
        o4[j] = (__bf16)fmaxf(x, 0.f);
    }
    *(uint2*)(out + off) = *(uint2*)o4;
}

// ========= fc2: bf16 MFMA GEMM 64x64, fused bias/bn/relu, reg-prefetch =======
__global__ __launch_bounds__(256) void k_fc2_mfma(
    const __bf16* __restrict__ A, const __bf16* __restrict__ W,
    const float* __restrict__ bias,
    const float* __restrict__ bng, const float* __restrict__ bnb,
    const float* __restrict__ bnm, const float* __restrict__ bnv,
    __bf16* __restrict__ out) {
    const int t = threadIdx.x;
    const int lane = t & 63, w = t >> 6;
    const int q = lane >> 4, li = lane & 15;
    const int m0 = blockIdx.x * 64, n0 = blockIdx.y * 64;
    const int wm = (w & 1) * 32, wn = (w >> 1) * 32;
    const int K = 512, N = 512;

    __shared__ __align__(16) __bf16 As[64 * 40];
    __shared__ __align__(16) __bf16 Bs[64 * 40];

    f32x4 acc[2][2];
#pragma unroll
    for (int i = 0; i < 2; ++i)
#pragma unroll
        for (int j = 0; j < 2; ++j) acc[i][j] = (f32x4){0.f, 0.f, 0.f, 0.f};

    const int row = (t & 127) >> 1, half = t & 1;
    const __bf16* g = (t < 128 ? A + (size_t)(m0 + row) * K
                               : W + (size_t)(n0 + row) * K) + half * 16;
    __bf16* ld = (t < 128 ? As : Bs) + row * 40 + half * 16;

    bf16x8 p0 = *(const bf16x8*)g;
    bf16x8 p1 = *(const bf16x8*)(g + 8);
    for (int k0 = 0; k0 < K; k0 += 32) {
        *(bf16x8*)ld = p0;
        *(bf16x8*)(ld + 8) = p1;
        __syncthreads();
        g += 32;
        if (k0 + 32 < K) {
            p0 = *(const bf16x8*)g;
            p1 = *(const bf16x8*)(g + 8);
        }
        bf16x8 af[2], bfr[2];
#pragma unroll
        for (int i = 0; i < 2; ++i)
            af[i] = *(const bf16x8*)&As[(wm + i * 16 + li) * 40 + q * 8];
#pragma unroll
        for (int j = 0; j < 2; ++j)
            bfr[j] = *(const bf16x8*)&Bs[(wn + j * 16 + li) * 40 + q * 8];
#pragma unroll
        for (int i = 0; i < 2; ++i)
#pragma unroll
            for (int j = 0; j < 2; ++j)
                acc[i][j] = mfma16(af[i], bfr[j], acc[i][j]);
        __syncthreads();
    }
    float bi[2], sc[2], hh[2];
#pragma unroll
    for (int j = 0; j < 2; ++j) {
        int n = n0 + wn + j * 16 + li;
        bi[j] = bias[n];
        sc[j] = bng[n] * rsqrtf(bnv[n] + EPS);
        hh[j] = bnb[n] - bnm[n] * sc[j];
    }
#pragma unroll
    for (int i = 0; i < 2; ++i) {
#pragma unroll
        for (int r = 0; r < 4; ++r) {
            int m = m0 + wm + i * 16 + q * 4 + r;
#pragma unroll
            for (int j = 0; j < 2; ++j) {
                int n = n0 + wn + j * 16 + li;
                float x = (acc[i][j][r] + bi[j]) * sc[j] + hh[j];
                out[(size_t)m * N + n] = (__bf16)fmaxf(x, 0.f);
            }
        }
    }
}

// ========= fused fc3 + bn + relu + out layer -> fp32 d_out ===================
// grid 24 blocks, 64 samples each; fc3: 64x128 K=512, out: 64x128 K=128
__global__ __launch_bounds__(256) void k_fc3out(
    const __bf16* __restrict__ A, const __bf16* __restrict__ W3,
    const __bf16* __restrict__ Wo,
    const float* __restrict__ b3,
    const float* __restrict__ bng, const float* __restrict__ bnb,
    const float* __restrict__ bnm, const float* __restrict__ bnv,
    const float* __restrict__ bo, float* __restrict__ out) {
    const int t = threadIdx.x;
    const int lane = t & 63, w = t >> 6;
    const int q = lane >> 4, li = lane & 15;
    const int m0 = blockIdx.x * 64;
    const int wn = w * 32;                 // wave covers 32 of N=128

    __shared__ __align__(16) __bf16 As[64 * 40];
    __shared__ __align__(16) __bf16 Bs[128 * 40];
    __shared__ __align__(16) __bf16 ysb[64 * 136];

    const int rowA = (t & 127) >> 1, rowB = t >> 1, half = t & 1;
    const __bf16* Ag = A + (size_t)(m0 + rowA) * 512 + half * 16;
    const __bf16* Bg = W3 + (size_t)rowB * 512 + half * 16;

    f32x4 acc[4][2];
#pragma unroll
    for (int i = 0; i < 4; ++i)
#pragma unroll
        for (int j = 0; j < 2; ++j) acc[i][j] = (f32x4){0.f, 0.f, 0.f, 0.f};

    bf16x8 pa0, pa1, pb0, pb1;
    pb0 = *(const bf16x8*)Bg;
    pb1 = *(const bf16x8*)(Bg + 8);
    if (t < 128) {
        pa0 = *(const bf16x8*)Ag;
        pa1 = *(const bf16x8*)(Ag + 8);
    }
    for (int step = 0; step < 16; ++step) {
        if (t < 128) {
            *(bf16x8*)&As[rowA * 40 + half * 16] = pa0;
            *(bf16x8*)&As[rowA * 40 + half * 16 + 8] = pa1;
        }
        *(bf16x8*)&Bs[rowB * 40 + half * 16] = pb0;
        *(bf16x8*)&Bs[rowB * 40 + half * 16 + 8] = pb1;
        __syncthreads();
        Ag += 32; Bg += 32;
        if (step < 15) {
            pb0 = *(const bf16x8*)Bg;
            pb1 = *(const bf16x8*)(Bg + 8);
            if (t < 128) {
                pa0 = *(const bf16x8*)Ag;
                pa1 = *(const bf16x8*)(Ag + 8);
            }
        }
        bf16x8 af[4], bfr[2];
#pragma unroll
        for (int i = 0; i < 4; ++i)
            af[i] = *(const bf16x8*)&As[(i * 16 + li) * 40 + q * 8];
#pragma unroll
        for (int j = 0; j < 2; ++j)
            bfr[j] = *(const bf16x8*)&Bs[(wn + j * 16 + li) * 40 + q * 8];
#pragma unroll
        for (int i = 0; i < 4; ++i)
#pragma unroll
            for (int j = 0; j < 2; ++j)
                acc[i][j] = mfma16(af[i], bfr[j], acc[i][j]);
        __syncthreads();
    }
    {   // fc3 epilogue -> ysb (bf16, stride 136)
#pragma unroll
        for (int j = 0; j < 2; ++j) {
            int n = wn + j * 16 + li;
            float sc = bng[n] * rsqrtf(bnv[n] + EPS);
            float hh = bnb[n] - bnm[n] * sc;
            float bi = b3[n];
#pragma unroll
            for (int i = 0; i < 4; ++i)
#pragma unroll
                for (int r = 0; r < 4; ++r) {
                    int ml = i * 16 + q * 4 + r;
                    float x = (acc[i][j][r] + bi) * sc + hh;
                    ysb[ml * 136 + n] = (__bf16)fmaxf(x, 0.f);
                }
        }
    }
    __syncthreads();
    // out layer: M=64, N=128, K=128 from ysb
    f32x4 acc2[4][2];
#pragma unroll
    for (int i = 0; i < 4; ++i)
#pragma unroll
        for (int j = 0; j < 2; ++j) acc2[i][j] = (f32x4){0.f, 0.f, 0.f, 0.f};
    const __bf16* Bg2 = Wo + (size_t)rowB * 128 + half * 16;
#pragma unroll
    for (int step = 0; step < 4; ++step) {
        *(bf16x8*)&Bs[rowB * 40 + half * 16] = *(const bf16x8*)(Bg2 + step * 32);
        *(bf16x8*)&Bs[rowB * 40 + half * 16 + 8] = *(const bf16x8*)(Bg2 + step * 32 + 8);
        __syncthreads();
        bf16x8 af[4], bfr[2];
#pragma unroll
        for (int i = 0; i < 4; ++i)
            af[i] = *(const bf16x8*)&ysb[(i * 16 + li) * 136 + step * 32 + q * 8];
#pragma unroll
        for (int j = 0; j < 2; ++j)
            bfr[j] = *(const bf16x8*)&Bs[(wn + j * 16 + li) * 40 + q * 8];
#pragma unroll
        for (int i = 0; i < 4; ++i)
#pragma unroll
            for (int j = 0; j < 2; ++j)
                acc2[i][j] = mfma16(af[i], bfr[j], acc2[i][j]);
        __syncthreads();
    }
#pragma unroll
    for (int j = 0; j < 2; ++j) {
        int n = wn + j * 16 + li;
        float bi = bo[n];
#pragma unroll
        for (int i = 0; i < 4; ++i)
#pragma unroll
            for (int r = 0; r < 4; ++r) {
                int m = m0 + i * 16 + q * 4 + r;
                out[(size_t)m * 128 + n] = acc2[i][j][r] + bi;
            }
    }
}

extern "C" void kernel_launch(void* const* d_in, const int* in_sizes, int n_in,
                              void* d_out, int out_size, void* d_ws, size_t ws_size,
                              hipStream_t stream) {
    const float* inA    = (const float*)d_in[0];
    const float* inP    = (const float*)d_in[1];
    const float* inN    = (const float*)d_in[2];
    const float* bn0g   = (const float*)d_in[3];
    const float* bn0b   = (const float*)d_in[4];
    const float* bn0m   = (const float*)d_in[5];
    const float* bn0v   = (const float*)d_in[6];
    const float* conv1w = (const float*)d_in[7];
    const float* conv1b = (const float*)d_in[8];
    const float* bn1g   = (const float*)d_in[9];
    const float* bn1b   = (const float*)d_in[10];
    const float* bn1m   = (const float*)d_in[11];
    const float* bn1v   = (const float*)d_in[12];
    const float* conv2w = (const float*)d_in[13];
    const float* conv2b = (const float*)d_in[14];
    const float* bn2g   = (const float*)d_in[15];
    const float* bn2b   = (const float*)d_in[16];
    const float* bn2m   = (const float*)d_in[17];
    const float* bn2v   = (const float*)d_in[18];
    const float* lc1w   = (const float*)d_in[19];
    const float* bn3g   = (const float*)d_in[20];
    const float* bn3b   = (const float*)d_in[21];
    const float* bn3m   = (const float*)d_in[22];
    const float* bn3v   = (const float*)d_in[23];
    const float* lc2w   = (const float*)d_in[24];
    const float* bn4g   = (const float*)d_in[25];
    const float* bn4b   = (const float*)d_in[26];
    const float* bn4m   = (const float*)d_in[27];
    const float* bn4v   = (const float*)d_in[28];
    const float* fc1w   = (const float*)d_in[29];
    const float* fc1b   = (const float*)d_in[30];
    const float* bnf1g  = (const float*)d_in[31];
    const float* bnf1b  = (const float*)d_in[32];
    const float* bnf1m  = (const float*)d_in[33];
    const float* bnf1v  = (const float*)d_in[34];
    const float* fc2w   = (const float*)d_in[35];
    const float* fc2b   = (const float*)d_in[36];
    const float* bnf2g  = (const float*)d_in[37];
    const float* bnf2b  = (const float*)d_in[38];
    const float* bnf2m  = (const float*)d_in[39];
    const float* bnf2v  = (const float*)d_in[40];
    const float* fc3w   = (const float*)d_in[41];
    const float* fc3b   = (const float*)d_in[42];
    const float* bnf3g  = (const float*)d_in[43];
    const float* bnf3b  = (const float*)d_in[44];
    const float* bnf3m  = (const float*)d_in[45];
    const float* bnf3v  = (const float*)d_in[46];
    const float* outw   = (const float*)d_in[47];
    const float* outb   = (const float*)d_in[48];

    char* wsb = (char*)d_ws;
    __bf16* w1frag  = (__bf16*)wsb;                        // 2048 el
    __bf16* w2frag  = w1frag + 2048;                       // 36864 el
    __bf16* lc1frag = w2frag + 36864;                      // 524288 el
    __bf16* lc2frag = lc1frag + 524288;                    // 524288 el
    __bf16* fc1Wb   = lc2frag + 524288;                    // 4194304 el
    __bf16* wf23    = fc1Wb + 4194304;                     // 344064 el
    __bf16* act     = wf23 + 344064;                       // 12582912 el
    __bf16* act3    = act + 12582912;                      // 786432 el
    __bf16* act4    = act3 + 786432;                       // 786432 el
    float*  part    = (float*)(((uintptr_t)(act4 + 786432) + 15) & ~(uintptr_t)15);
    __bf16* wf2 = wf23;
    __bf16* wf3 = wf23 + 262144;
    __bf16* wfo = wf23 + 327680;

    // ---- all weight prep, one launch ----
    k_prep_all<<<2003, 256, 0, stream>>>(conv1w, conv2w, lc1w, lc2w,
        fc1w, fc2w, fc3w, outw, w1frag, w2frag, lc1frag, lc2frag, fc1Wb, wf23);

    // ---- conv stage ----
    k_conv_mfma<<<1536, 256, 0, stream>>>(inA, inP, inN,
        bn0g, bn0b, bn0m, bn0v, w1frag, conv1b, bn1g, bn1b, bn1m, bn1v,
        w2frag, conv2b, bn2g, bn2b, bn2m, bn2v, act);

    // ---- locally connected (in place) ----
    k_lc_mfma<<<dim3(128, 24), 256, 0, stream>>>(lc1frag, lc2frag,
        bn3g, bn3b, bn3m, bn3v, bn4g, bn4b, bn4m, bn4v, act);

    // ---- fc1 (split-K 8) + reduce ----
    k_fc1_mfma<<<dim3(24, 4, 8), 256, 0, stream>>>(act, fc1Wb, part);
    k_fc1_reduce<<<768, 256, 0, stream>>>(part, fc1b, bnf1g, bnf1b, bnf1m, bnf1v, act3);

    // ---- fc2 ----
    k_fc2_mfma<<<dim3(24, 8), 256, 0, stream>>>(act3, wf2, fc2b,
        bnf2g, bnf2b, bnf2m, bnf2v, act4);

    // ---- fc3 + out fused ----
    k_fc3out<<<24, 256, 0, stream>>>(act4, wf3, wfo, fc3b,
        bnf3g, bnf3b, bnf3m, bnf3v, outb, (float*)d_out);
}